// Round 6
// baseline (438.768 us; speedup 1.0000x reference)
//
#include <hip/hip_runtime.h>
#include <hip/hip_bf16.h>
#include <math.h>
#include <stdint.h>

// Problem constants
#define BATCH    2
#define SEQ      2048
#define DMODEL   1024
#define DSSM     2048
#define NHEADS   32
#define DHEAD    64
#define DSTATE   128
#define CONVDIM  2304     // DSSM + 2*DSTATE
#define DINPROJ  4384     // 2*2048 + 2*128 + 32
#define NPAD     4480     // DINPROJ padded to multiple of 128
#define CHUNK    256
#define NCHUNK   8
#define ROWS     (BATCH*SEQ)          // 4096
#define NBC      (BATCH*NCHUNK)       // 16
#define EPSF     1e-5f
#define CBASE    (DSSM + DSTATE)      // 2176, C columns in xbc
#define DTCOL    (DSSM + CONVDIM)     // 4352, dt_raw columns start

typedef _Float16 half8 __attribute__((ext_vector_type(8)));
typedef _Float16 half4 __attribute__((ext_vector_type(4)));
typedef float f32x4 __attribute__((ext_vector_type(4)));

// global_load_lds: 16B per lane, LDS dest = wave-uniform base + lane*16
static __device__ __forceinline__ void gload_lds16(const void* g, void* l) {
    __builtin_amdgcn_global_load_lds(
        (const __attribute__((address_space(1))) uint32_t*)g,
        (__attribute__((address_space(3))) uint32_t*)l, 16, 0, 0);
}

// ---------------------------------------------------------------------------
// MFMA GEMM (f16 in): C[M,N] = A[M,K] * B[N,K]^T.  BK=64, XOR-swizzled LDS,
// XCD-aware block swizzle. HOUT: store f16 (plus f32 side-channel for the
// dt_raw columns into dtraw). !HOUT: store f32.
// ---------------------------------------------------------------------------
template<int WM, int WN, bool HOUT>
__global__ __launch_bounds__(256) void gemm_f16(const _Float16* __restrict__ A,
                                                const _Float16* __restrict__ B,
                                                void* __restrict__ Cout,
                                                float* __restrict__ dtraw,
                                                int K, int ldc, int Nc) {
    constexpr int BM = 32 * WM;
    constexpr int BN = 32 * WN;
    __shared__ _Float16 As[BM * 64];
    __shared__ _Float16 Bs[BN * 64];
    const int t  = threadIdx.x;
    const int wv = t >> 6;
    const int ln = t & 63;
    const int wr = wv >> 1, wc = wv & 1;

    // XCD-aware swizzle (nwg % 8 == 0 for all our grids)
    int nwg = gridDim.x * gridDim.y;
    int bid0 = blockIdx.y * gridDim.x + blockIdx.x;
    int qq = nwg >> 3;
    int swz = (bid0 & 7) * qq + (bid0 >> 3);
    const int tm = (swz / gridDim.x) * BM;
    const int bn = (swz % gridDim.x) * BN;

    const int kb = ln >> 4;          // 0..3
    const int lr = ln & 15;
    const int srow = ln >> 3;
    const int susw = (ln & 7) ^ srow;

    f32x4 acc[WM][WN];
    #pragma unroll
    for (int i = 0; i < WM; ++i)
        #pragma unroll
        for (int j = 0; j < WN; ++j) { f32x4 z = {0.f, 0.f, 0.f, 0.f}; acc[i][j] = z; }

    for (int k0 = 0; k0 < K; k0 += 64) {
        #pragma unroll
        for (int q = 0; q < BM / 32; ++q) {
            int seg = q * 4 + wv;
            int row = seg * 8 + srow;
            const _Float16* src = A + (size_t)(tm + row) * K + k0 + susw * 8;
            gload_lds16(src, (void*)(As + seg * 512));
        }
        #pragma unroll
        for (int q = 0; q < BN / 32; ++q) {
            int seg = q * 4 + wv;
            int row = seg * 8 + srow;
            const _Float16* src = B + (size_t)(bn + row) * K + k0 + susw * 8;
            gload_lds16(src, (void*)(Bs + seg * 512));
        }
        __syncthreads();

        #pragma unroll
        for (int ks = 0; ks < 2; ++ks) {
            half8 af[WM], bf[WN];
            #pragma unroll
            for (int mi = 0; mi < WM; ++mi) {
                int r = wr * (16 * WM) + mi * 16 + lr;
                af[mi] = *(const half8*)(As + r * 64 + (((ks * 4 + kb) ^ (r & 7)) << 3));
            }
            #pragma unroll
            for (int ni = 0; ni < WN; ++ni) {
                int r = wc * (16 * WN) + ni * 16 + lr;
                bf[ni] = *(const half8*)(Bs + r * 64 + (((ks * 4 + kb) ^ (r & 7)) << 3));
            }
            #pragma unroll
            for (int mi = 0; mi < WM; ++mi)
                #pragma unroll
                for (int ni = 0; ni < WN; ++ni)
                    acc[mi][ni] = __builtin_amdgcn_mfma_f32_16x16x32_f16(af[mi], bf[ni], acc[mi][ni], 0, 0, 0);
        }
        __syncthreads();
    }

    #pragma unroll
    for (int mi = 0; mi < WM; ++mi) {
        #pragma unroll
        for (int ni = 0; ni < WN; ++ni) {
            int col = bn + wc * (16 * WN) + ni * 16 + lr;
            if (col < Nc) {
                int row = tm + wr * (16 * WM) + mi * 16 + (ln >> 4) * 4;
                if (HOUT) {
                    _Float16* C = (_Float16*)Cout;
                    #pragma unroll
                    for (int r = 0; r < 4; ++r)
                        C[(size_t)(row + r) * ldc + col] = (_Float16)acc[mi][ni][r];
                    if (col >= DTCOL) {
                        #pragma unroll
                        for (int r = 0; r < 4; ++r)
                            dtraw[(size_t)(row + r) * NHEADS + (col - DTCOL)] = acc[mi][ni][r];
                    }
                } else {
                    float* C = (float*)Cout;
                    #pragma unroll
                    for (int r = 0; r < 4; ++r)
                        C[(size_t)(row + r) * ldc + col] = acc[mi][ni][r];
                }
            }
        }
    }
}

// ---------------------------------------------------------------------------
// casts
// ---------------------------------------------------------------------------
__global__ __launch_bounds__(256) void cast_f16_kernel(const float* __restrict__ src,
                                                       _Float16* __restrict__ dst, int n8) {
    int i = blockIdx.x * 256 + threadIdx.x;
    if (i >= n8) return;
    float4 a = ((const float4*)src)[2 * i];
    float4 b = ((const float4*)src)[2 * i + 1];
    half8 h;
    h[0] = (_Float16)a.x; h[1] = (_Float16)a.y; h[2] = (_Float16)a.z; h[3] = (_Float16)a.w;
    h[4] = (_Float16)b.x; h[5] = (_Float16)b.y; h[6] = (_Float16)b.z; h[7] = (_Float16)b.w;
    ((half8*)dst)[i] = h;
}

__global__ __launch_bounds__(256) void cast_pad_f16_kernel(const float* __restrict__ src,
                                                           _Float16* __restrict__ dst,
                                                           int srcRows, int cols, int n8) {
    int i = blockIdx.x * 256 + threadIdx.x;
    if (i >= n8) return;
    int row = (i * 8) / cols;
    half8 h;
    if (row < srcRows) {
        float4 a = ((const float4*)src)[2 * i];
        float4 b = ((const float4*)src)[2 * i + 1];
        h[0] = (_Float16)a.x; h[1] = (_Float16)a.y; h[2] = (_Float16)a.z; h[3] = (_Float16)a.w;
        h[4] = (_Float16)b.x; h[5] = (_Float16)b.y; h[6] = (_Float16)b.z; h[7] = (_Float16)b.w;
    } else {
        #pragma unroll
        for (int q = 0; q < 8; ++q) h[q] = (_Float16)0.f;
    }
    ((half8*)dst)[i] = h;
}

// ---------------------------------------------------------------------------
// Conv + SiLU (f16 zx input), tiled with LDS transpose.
// ---------------------------------------------------------------------------
__global__ __launch_bounds__(256) void conv_silu_kernel(const _Float16* __restrict__ zx,
                                                        const float* __restrict__ conv_w,
                                                        const float* __restrict__ conv_b,
                                                        _Float16* __restrict__ xbc,
                                                        _Float16* __restrict__ xTg,
                                                        _Float16* __restrict__ BTg) {
    __shared__ float zs[67 * 64];
    __shared__ float os[64 * 65];
    const int bid = blockIdx.x;
    const int cg = bid % 36;
    const int bc = bid / 36;
    const int b = bc >> 3, cloc = bc & 7;
    const int c0 = cg * 64;
    const int t = threadIdx.x;

    const int cc = c0 + (t & 63);
    const float w0 = conv_w[cc * 4 + 0], w1 = conv_w[cc * 4 + 1];
    const float w2 = conv_w[cc * 4 + 2], w3 = conv_w[cc * 4 + 3];
    const float bias = conv_b[cc];

    for (int lt = 0; lt < 4; ++lt) {
        const int lbase = cloc * 256 + lt * 64;
        __syncthreads();
        for (int i = t; i < 67 * 64; i += 256) {
            int r = i >> 6, col = i & 63;
            int lseq = lbase - 3 + r;
            float v = 0.f;
            if (lseq >= 0)
                v = (float)zx[((size_t)(b * SEQ + lseq)) * DINPROJ + DSSM + c0 + col];
            zs[i] = v;
        }
        __syncthreads();
        {
            int c = t & 63;
            int w = t >> 6;
            #pragma unroll
            for (int j = 0; j < 16; ++j) {
                int l = w * 16 + j;
                float acc = bias + zs[(l + 0) * 64 + c] * w0 + zs[(l + 1) * 64 + c] * w1
                                 + zs[(l + 2) * 64 + c] * w2 + zs[(l + 3) * 64 + c] * w3;
                os[l * 65 + c] = acc / (1.f + expf(-acc));
            }
        }
        __syncthreads();
        {
            int l = t >> 2, cs = (t & 3) * 16;
            size_t m = (size_t)(b * SEQ + lbase + l);
            half8 h0, h1;
            #pragma unroll
            for (int i = 0; i < 8; ++i) h0[i] = (_Float16)os[l * 65 + cs + i];
            #pragma unroll
            for (int i = 0; i < 8; ++i) h1[i] = (_Float16)os[l * 65 + cs + 8 + i];
            _Float16* dst = xbc + m * CONVDIM + c0 + cs;
            *(half8*)dst = h0;
            *(half8*)(dst + 8) = h1;
        }
        if (c0 < CBASE) {
            int c = t >> 2, ls = (t & 3) * 16;
            int gc = c0 + c;
            half8 h0, h1;
            #pragma unroll
            for (int i = 0; i < 8; ++i) h0[i] = (_Float16)os[(ls + i) * 65 + c];
            #pragma unroll
            for (int i = 0; i < 8; ++i) h1[i] = (_Float16)os[(ls + 8 + i) * 65 + c];
            _Float16* dst;
            if (gc < DSSM)
                dst = xTg + ((size_t)bc * 2048 + gc) * 256 + lt * 64 + ls;
            else
                dst = BTg + ((size_t)bc * 128 + (gc - DSSM)) * 256 + lt * 64 + ls;
            *(half8*)dst = h0;
            *(half8*)(dst + 8) = h1;
        }
    }
}

// ---------------------------------------------------------------------------
// Fused dt = softplus(dt_raw + bias) and per-chunk cumsum of dA.
// dtraw is the f32 side-channel written by the in_proj GEMM.
// ---------------------------------------------------------------------------
__global__ void dtcum_kernel(const float* __restrict__ dtraw,
                             const float* __restrict__ dt_bias,
                             const float* __restrict__ A_log,
                             float* __restrict__ dtb,
                             float* __restrict__ cum) {
    int t = blockIdx.x * 256 + threadIdx.x;
    if (t >= NBC * NHEADS) return;
    int h = t & 31;
    int bc = t >> 5;
    float bias = dt_bias[h];
    float A = -expf(A_log[h]);
    float acc = 0.f;
    for (int l = 0; l < CHUNK; ++l) {
        size_t idx = ((size_t)bc * CHUNK + l) * NHEADS + h;
        float v = dtraw[idx] + bias;
        float d = (v > 20.f) ? v : log1pf(expf(v));
        dtb[idx] = d;
        acc += d * A;
        cum[idx] = acc;
    }
}

// ---------------------------------------------------------------------------
// Chunk states via MFMA: S[p][n] = sum_l (coef[l]*x[l,p]) * B[l,n]
// ---------------------------------------------------------------------------
__global__ __launch_bounds__(256) void chunk_state_mfma(const _Float16* __restrict__ xTg,
                                                        const _Float16* __restrict__ BTg,
                                                        const float* __restrict__ dt,
                                                        const float* __restrict__ cum,
                                                        float* __restrict__ S) {
    int bid = blockIdx.x;
    int h = bid & 31, bc = bid >> 5;
    __shared__ _Float16 cxs[64 * 64];
    __shared__ _Float16 bts[128 * 64];
    __shared__ float coefL[256];
    const int t = threadIdx.x, w = t >> 6, ln = t & 63;
    const int lr = ln & 15, lg = ln >> 4;

    {
        float cl = cum[((size_t)bc * 256 + 255) * 32 + h];
        size_t ci = ((size_t)bc * 256 + t) * 32 + h;
        coefL[t] = expf(cl - cum[ci]) * dt[ci];
    }

    f32x4 sacc[4][2];
    #pragma unroll
    for (int pi = 0; pi < 4; ++pi)
        #pragma unroll
        for (int ni = 0; ni < 2; ++ni) { f32x4 z = {0.f,0.f,0.f,0.f}; sacc[pi][ni] = z; }

    const _Float16* xTh = xTg + (size_t)bid * 64 * 256;

    for (int kt = 0; kt < 4; ++kt) {
        __syncthreads();
        {
            int p = t >> 2, l0 = (t & 3) * 16;
            const _Float16* src = xTh + (size_t)p * 256 + kt * 64;
            #pragma unroll
            for (int q = 0; q < 2; ++q) {
                int c = l0 + q * 8;
                half8 hv = *(const half8*)(src + c);
                half8 ov;
                #pragma unroll
                for (int j = 0; j < 8; ++j)
                    ov[j] = (_Float16)((float)hv[j] * coefL[kt * 64 + c + j]);
                *(half8*)(cxs + p * 64 + (c ^ ((p & 7) << 3))) = ov;
            }
        }
        #pragma unroll
        for (int q = 0; q < 4; ++q) {
            int seg = w * 4 + q;
            int r = seg * 8 + (ln >> 3);
            int csw = 8 * ((ln & 7) ^ (r & 7));
            const _Float16* src = BTg + ((size_t)bc * 128 + r) * 256 + kt * 64 + csw;
            gload_lds16(src, (void*)(bts + seg * 512));
        }
        __syncthreads();
        #pragma unroll
        for (int kk = 0; kk < 2; ++kk) {
            int c0 = kk * 32 + lg * 8;
            half8 ax[4], bx[2];
            #pragma unroll
            for (int pi = 0; pi < 4; ++pi) {
                int r = pi * 16 + lr;
                ax[pi] = *(const half8*)(cxs + r * 64 + (c0 ^ ((r & 7) << 3)));
            }
            #pragma unroll
            for (int ni = 0; ni < 2; ++ni) {
                int r = w * 32 + ni * 16 + lr;
                bx[ni] = *(const half8*)(bts + r * 64 + (c0 ^ ((r & 7) << 3)));
            }
            #pragma unroll
            for (int pi = 0; pi < 4; ++pi)
                #pragma unroll
                for (int ni = 0; ni < 2; ++ni)
                    sacc[pi][ni] = __builtin_amdgcn_mfma_f32_16x16x32_f16(ax[pi], bx[ni], sacc[pi][ni], 0, 0, 0);
        }
    }
    float* sb = S + (size_t)bid * (DHEAD * DSTATE);
    #pragma unroll
    for (int pi = 0; pi < 4; ++pi)
        #pragma unroll
        for (int ni = 0; ni < 2; ++ni)
            #pragma unroll
            for (int r = 0; r < 4; ++r) {
                int p = pi * 16 + lg * 4 + r;
                int n = w * 32 + ni * 16 + lr;
                sb[p * 128 + n] = sacc[pi][ni][r];
            }
}

// ---------------------------------------------------------------------------
// Inter-chunk scan; S[c] <- state ENTERING chunk c.
// ---------------------------------------------------------------------------
__global__ __launch_bounds__(256) void scan_kernel(const float* __restrict__ cum,
                                                   float* __restrict__ S) {
    int bid = blockIdx.x;
    int h = bid & 31, b = bid >> 5;
    int t = threadIdx.x;
    float carry[32];
    #pragma unroll
    for (int i = 0; i < 32; ++i) carry[i] = 0.f;
    for (int c = 0; c < NCHUNK; ++c) {
        int bc = b * NCHUNK + c;
        float decay = expf(cum[((size_t)bc * CHUNK + 255) * NHEADS + h]);
        size_t base = ((size_t)(bc * NHEADS + h)) * (DHEAD * DSTATE);
        #pragma unroll
        for (int i = 0; i < 32; ++i) {
            size_t idx = base + t + i * 256;
            float s = S[idx];
            float nw = carry[i] * decay + s;
            S[idx] = carry[i];
            carry[i] = nw;
        }
    }
}

// ---------------------------------------------------------------------------
// Y via MFMA v2
// ---------------------------------------------------------------------------
__global__ __launch_bounds__(256, 2) void y_mfma(const _Float16* __restrict__ xbc,
                                                 const _Float16* __restrict__ xTg,
                                                 const float* __restrict__ dt,
                                                 const float* __restrict__ cum,
                                                 const float* __restrict__ Sprev,
                                                 const float* __restrict__ Dp,
                                                 float* __restrict__ y) {
    int bid = blockIdx.x;
    int h = bid & 31, bc = bid >> 5;
    __shared__ _Float16 Bs2[2][64 * 128];
    __shared__ _Float16 PwF[4 * 64 * 64];
    __shared__ float cumL[256], dtL[256];
    const int t = threadIdx.x, w = t >> 6, ln = t & 63;
    const int lr = ln & 15, lg = ln >> 4;

    {
        size_t ci = ((size_t)bc * 256 + t) * 32 + h;
        cumL[t] = cum[ci];
        dtL[t]  = dt[ci];
    }
    {
        const float* sp = Sprev + (size_t)bid * (DHEAD * DSTATE);
        int r = t >> 2, cb = (t & 3) * 32;
        #pragma unroll
        for (int q = 0; q < 4; ++q) {
            int c = cb + q * 8;
            float4 f0 = *(const float4*)(sp + r * 128 + c);
            float4 f1 = *(const float4*)(sp + r * 128 + c + 4);
            half8 hv;
            hv[0]=(_Float16)f0.x; hv[1]=(_Float16)f0.y; hv[2]=(_Float16)f0.z; hv[3]=(_Float16)f0.w;
            hv[4]=(_Float16)f1.x; hv[5]=(_Float16)f1.y; hv[6]=(_Float16)f1.z; hv[7]=(_Float16)f1.w;
            *(half8*)(PwF + r * 128 + (c ^ ((r & 7) << 3))) = hv;
        }
    }
    {
        #pragma unroll
        for (int q = 0; q < 4; ++q) {
            int seg = w * 4 + q;
            int r = seg * 4 + lg;
            int csw = 8 * (lr ^ (r & 7));
            const _Float16* src = xbc + ((size_t)(bc * 256 + r)) * CONVDIM + DSSM + csw;
            gload_lds16(src, (void*)(Bs2[0] + seg * 512));
        }
    }
    half8 ca[4][4];
    {
        const _Float16* cb = xbc + ((size_t)(bc * 256 + w * 64)) * CONVDIM + CBASE;
        #pragma unroll
        for (int mi = 0; mi < 4; ++mi)
            #pragma unroll
            for (int kk = 0; kk < 4; ++kk)
                ca[mi][kk] = *(const half8*)(cb + (size_t)(mi * 16 + lr) * CONVDIM + kk * 32 + lg * 8);
    }
    __syncthreads();

    f32x4 yacc[4][4];
    #pragma unroll
    for (int i = 0; i < 4; ++i)
        #pragma unroll
        for (int j = 0; j < 4; ++j) { f32x4 z = {0.f,0.f,0.f,0.f}; yacc[i][j] = z; }

    #pragma unroll
    for (int kk = 0; kk < 4; ++kk) {
        int co = kk * 32 + lg * 8;
        #pragma unroll
        for (int pi = 0; pi < 4; ++pi) {
            int r = pi * 16 + lr;
            half8 pb = *(const half8*)(PwF + r * 128 + (co ^ ((r & 7) << 3)));
            #pragma unroll
            for (int mi = 0; mi < 4; ++mi)
                yacc[mi][pi] = __builtin_amdgcn_mfma_f32_16x16x32_f16(ca[mi][kk], pb, yacc[mi][pi], 0, 0, 0);
        }
    }
    #pragma unroll
    for (int mi = 0; mi < 4; ++mi)
        #pragma unroll
        for (int r = 0; r < 4; ++r) {
            float e = expf(cumL[w * 64 + mi * 16 + lg * 4 + r]);
            #pragma unroll
            for (int pi = 0; pi < 4; ++pi) yacc[mi][pi][r] *= e;
        }
    float c0 = cumL[w * 64];
    float el[4];
    #pragma unroll
    for (int mi = 0; mi < 4; ++mi) el[mi] = expf(cumL[w * 64 + mi * 16 + lr] - c0);
    float Dv = Dp[h];

    __syncthreads();

    _Float16* pwb = PwF + w * 4096;
    for (int st = 0; st < 4; ++st) {
        if (st < 3) {
            #pragma unroll
            for (int q = 0; q < 4; ++q) {
                int seg = w * 4 + q;
                int r = seg * 4 + lg;
                int csw = 8 * (lr ^ (r & 7));
                const _Float16* src = xbc + ((size_t)(bc * 256 + (st + 1) * 64 + r)) * CONVDIM + DSSM + csw;
                gload_lds16(src, (void*)(Bs2[(st + 1) & 1] + seg * 512));
            }
        }
        if (st <= w) {
            const _Float16* bsc = Bs2[st & 1];
            half8 xb[4][2];
            #pragma unroll
            for (int pi = 0; pi < 4; ++pi)
                #pragma unroll
                for (int k2 = 0; k2 < 2; ++k2)
                    xb[pi][k2] = *(const half8*)(xTg + ((size_t)bid * 64 + pi * 16 + lr) * 256
                                                 + st * 64 + k2 * 32 + lg * 8);
            #pragma unroll
            for (int si = 0; si < 4; ++si) {
                f32x4 ps[4];
                #pragma unroll
                for (int mi = 0; mi < 4; ++mi) { f32x4 z = {0.f,0.f,0.f,0.f}; ps[mi] = z; }
                int r = si * 16 + lr;
                #pragma unroll
                for (int kk = 0; kk < 4; ++kk) {
                    int co = kk * 32 + lg * 8;
                    half8 bb = *(const half8*)(bsc + r * 128 + (co ^ ((r & 7) << 3)));
                    #pragma unroll
                    for (int mi = 0; mi < 4; ++mi)
                        ps[mi] = __builtin_amdgcn_mfma_f32_16x16x32_f16(bb, ca[mi][kk], ps[mi], 0, 0, 0);
                }
                if (st < w) {
                    float fs[4];
                    #pragma unroll
                    for (int rr = 0; rr < 4; ++rr) {
                        int sg = st * 64 + si * 16 + lg * 4 + rr;
                        fs[rr] = expf(c0 - cumL[sg]) * dtL[sg];
                    }
                    #pragma unroll
                    for (int mi = 0; mi < 4; ++mi) {
                        half4 hv;
                        #pragma unroll
                        for (int rr = 0; rr < 4; ++rr)
                            hv[rr] = (_Float16)(ps[mi][rr] * el[mi] * fs[rr]);
                        *(half4*)(pwb + (mi * 16 + lr) * 64 + ((si * 16 + lg * 4) ^ (8 * (lr & 7)))) = hv;
                    }
                } else {
                    #pragma unroll
                    for (int mi = 0; mi < 4; ++mi) {
                        int lloc = mi * 16 + lr;
                        float cl = cumL[w * 64 + lloc];
                        half4 hv;
                        #pragma unroll
                        for (int rr = 0; rr < 4; ++rr) {
                            int sl = si * 16 + lg * 4 + rr;
                            float v = 0.f;
                            if (sl <= lloc) {
                                int sg = w * 64 + sl;
                                v = ps[mi][rr] * expf(cl - cumL[sg]) * dtL[sg];
                                if (sl == lloc) v += Dv;
                            }
                            hv[rr] = (_Float16)v;
                        }
                        *(half4*)(pwb + (mi * 16 + lr) * 64 + ((si * 16 + lg * 4) ^ (8 * (lr & 7)))) = hv;
                    }
                }
            }
            #pragma unroll
            for (int k2 = 0; k2 < 2; ++k2) {
                int co = k2 * 32 + lg * 8;
                half8 pa[4];
                #pragma unroll
                for (int mi = 0; mi < 4; ++mi) {
                    int r = mi * 16 + lr;
                    pa[mi] = *(const half8*)(pwb + r * 64 + (co ^ (8 * (lr & 7))));
                }
                #pragma unroll
                for (int pi = 0; pi < 4; ++pi)
                    #pragma unroll
                    for (int mi = 0; mi < 4; ++mi)
                        yacc[mi][pi] = __builtin_amdgcn_mfma_f32_16x16x32_f16(pa[mi], xb[pi][k2], yacc[mi][pi], 0, 0, 0);
            }
        }
        __syncthreads();
    }

    #pragma unroll
    for (int mi = 0; mi < 4; ++mi) {
        #pragma unroll
        for (int r = 0; r < 4; ++r) {
            int l = w * 64 + mi * 16 + lg * 4 + r;
            size_t row = (size_t)bc * 256 + l;
            #pragma unroll
            for (int pi = 0; pi < 4; ++pi)
                y[row * DSSM + h * 64 + pi * 16 + lr] = yacc[mi][pi][r];
        }
    }
}

// ---------------------------------------------------------------------------
// Gated RMSNorm (f16 z input) -> f16 output for out_proj MFMA
// ---------------------------------------------------------------------------
__global__ __launch_bounds__(256) void norm_kernel(const float* __restrict__ y,
                                                   const _Float16* __restrict__ zx,
                                                   const float* __restrict__ norm_w,
                                                   _Float16* __restrict__ outh) {
    int m = blockIdx.x;
    int t = threadIdx.x;
    const float* yrow = y + (size_t)m * DSSM;
    const _Float16* zrow = zx + (size_t)m * DINPROJ;
    float yg[8];
    float ss = 0.f;
    half8 zv = *(const half8*)(zrow + t * 8);
    float4 yv0 = *(const float4*)(yrow + t * 8);
    float4 yv1 = *(const float4*)(yrow + t * 8 + 4);
    float yvals[8] = {yv0.x, yv0.y, yv0.z, yv0.w, yv1.x, yv1.y, yv1.z, yv1.w};
    #pragma unroll
    for (int i = 0; i < 8; ++i) {
        float z = (float)zv[i];
        float sz = z / (1.f + expf(-z));
        float g = yvals[i] * sz;
        yg[i] = g;
        ss += g * g;
    }
    #pragma unroll
    for (int off = 32; off > 0; off >>= 1) ss += __shfl_xor(ss, off, 64);
    __shared__ float red[4];
    if ((t & 63) == 0) red[t >> 6] = ss;
    __syncthreads();
    float tot = red[0] + red[1] + red[2] + red[3];
    float inv = rsqrtf(tot / (float)DSSM + EPSF);
    half8 h;
    #pragma unroll
    for (int q = 0; q < 8; ++q)
        h[q] = (_Float16)(yg[q] * inv * norm_w[t*8 + q]);
    *(half8*)(outh + (size_t)m * DSSM + t * 8) = h;
}

// ---------------------------------------------------------------------------
extern "C" void kernel_launch(void* const* d_in, const int* in_sizes, int n_in,
                              void* d_out, int out_size, void* d_ws, size_t ws_size,
                              hipStream_t stream) {
    (void)in_sizes; (void)n_in; (void)out_size; (void)ws_size;
    const float* u       = (const float*)d_in[0];
    const float* W_in    = (const float*)d_in[1];
    const float* conv_w  = (const float*)d_in[2];
    const float* conv_b  = (const float*)d_in[3];
    const float* dt_bias = (const float*)d_in[4];
    const float* A_log   = (const float*)d_in[5];
    const float* Dp      = (const float*)d_in[6];
    const float* norm_w  = (const float*)d_in[7];
    const float* W_out   = (const float*)d_in[8];
    float* out = (float*)d_out;

    // workspace layout: f32 region first, then f16 region
    float* dtraw = (float*)d_ws;                       // ROWS*32
    float* dtb   = dtraw + (size_t)ROWS * NHEADS;
    float* cum   = dtb   + (size_t)ROWS * NHEADS;
    float* Sbuf  = cum   + (size_t)ROWS * NHEADS;      // 512*64*128
    float* yb    = Sbuf  + (size_t)NBC * NHEADS * DHEAD * DSTATE;  // ROWS*DSSM
    _Float16* zxh   = (_Float16*)(yb + (size_t)ROWS * DSSM);       // ROWS*DINPROJ
    _Float16* xbc_h = zxh   + (size_t)ROWS * DINPROJ;              // ROWS*CONVDIM
    _Float16* xTg   = xbc_h + (size_t)ROWS * CONVDIM;              // 512*64*256
    _Float16* BTg   = xTg   + (size_t)NBC * NHEADS * 64 * 256;     // 16*128*256
    _Float16* uh    = BTg   + (size_t)NBC * 128 * 256;
    _Float16* Wih   = uh    + (size_t)ROWS * DMODEL;
    _Float16* Wouth = Wih   + (size_t)NPAD * DMODEL;
    _Float16* ybh   = Wouth + (size_t)DMODEL * DSSM;

    // casts
    cast_f16_kernel<<<(ROWS * DMODEL / 8 + 255) / 256, 256, 0, stream>>>(u, uh, ROWS * DMODEL / 8);
    cast_pad_f16_kernel<<<(NPAD * DMODEL / 8 + 255) / 256, 256, 0, stream>>>(
        W_in, Wih, DINPROJ, DMODEL, NPAD * DMODEL / 8);
    cast_f16_kernel<<<(DMODEL * DSSM / 8 + 255) / 256, 256, 0, stream>>>(W_out, Wouth, DMODEL * DSSM / 8);

    // 1. in_proj -> f16 zx (+ f32 dt_raw side-channel)
    gemm_f16<4, 4, true><<<dim3(NPAD / 128, ROWS / 128), 256, 0, stream>>>(
        uh, Wih, (void*)zxh, dtraw, DMODEL, DINPROJ, DINPROJ);
    // 2. conv + silu -> f16 xbc + transposed copies
    conv_silu_kernel<<<NBC * 36, 256, 0, stream>>>(
        zxh, conv_w, conv_b, xbc_h, xTg, BTg);
    // 3. dt + cumsum (fused, f32 path)
    dtcum_kernel<<<2, 256, 0, stream>>>(dtraw, dt_bias, A_log, dtb, cum);
    // 4. chunk states (MFMA)
    chunk_state_mfma<<<NBC * NHEADS, 256, 0, stream>>>(xTg, BTg, dtb, cum, Sbuf);
    // 5. inter-chunk scan
    scan_kernel<<<BATCH * NHEADS, 256, 0, stream>>>(cum, Sbuf);
    // 6. Y (MFMA v2)
    y_mfma<<<NBC * NHEADS, 256, 0, stream>>>(xbc_h, xTg, dtb, cum, Sbuf, Dp, yb);
    // 7. gated RMSNorm -> f16
    norm_kernel<<<ROWS, 256, 0, stream>>>(yb, zxh, norm_w, ybh);
    // 8. out_proj (f32 out)
    gemm_f16<4, 2, false><<<dim3(DMODEL / 64, ROWS / 128), 256, 0, stream>>>(
        ybh, Wouth, (void*)out, nullptr, DSSM, DMODEL, DMODEL);
}

// Round 7
// 300.053 us; speedup vs baseline: 1.4623x; 1.4623x over previous
//
#include <hip/hip_runtime.h>
#include <hip/hip_bf16.h>
#include <math.h>
#include <stdint.h>

// Problem constants
#define BATCH    2
#define SEQ      2048
#define DMODEL   1024
#define DSSM     2048
#define NHEADS   32
#define DHEAD    64
#define DSTATE   128
#define CONVDIM  2304     // DSSM + 2*DSTATE
#define DINPROJ  4384     // 2*2048 + 2*128 + 32
#define NPAD     4480     // DINPROJ padded to multiple of 128
#define CHUNK    256
#define NCHUNK   8
#define ROWS     (BATCH*SEQ)          // 4096
#define NBC      (BATCH*NCHUNK)       // 16
#define EPSF     1e-5f
#define CBASE    (DSSM + DSTATE)      // 2176, C columns in xbc
#define DTCOL    (DSSM + CONVDIM)     // 4352, dt_raw columns start

typedef _Float16 half8 __attribute__((ext_vector_type(8)));
typedef _Float16 half4 __attribute__((ext_vector_type(4)));
typedef float f32x4 __attribute__((ext_vector_type(4)));

// global_load_lds: 16B per lane, LDS dest = wave-uniform base + lane*16
static __device__ __forceinline__ void gload_lds16(const void* g, void* l) {
    __builtin_amdgcn_global_load_lds(
        (const __attribute__((address_space(1))) uint32_t*)g,
        (__attribute__((address_space(3))) uint32_t*)l, 16, 0, 0);
}

// ---------------------------------------------------------------------------
// MFMA GEMM (f16 in): C[M,N] = A[M,K] * B[N,K]^T.  BK=64, XOR-swizzled LDS,
// XCD-aware block swizzle. HOUT: store f16 + f32 h-major side-channel for
// the dt_raw columns (dtraw[h*ROWS + m]). !HOUT: store f32.
// ---------------------------------------------------------------------------
template<int WM, int WN, bool HOUT>
__global__ __launch_bounds__(256) void gemm_f16(const _Float16* __restrict__ A,
                                                const _Float16* __restrict__ B,
                                                void* __restrict__ Cout,
                                                float* __restrict__ dtraw,
                                                int K, int ldc, int Nc) {
    constexpr int BM = 32 * WM;
    constexpr int BN = 32 * WN;
    __shared__ _Float16 As[BM * 64];
    __shared__ _Float16 Bs[BN * 64];
    const int t  = threadIdx.x;
    const int wv = t >> 6;
    const int ln = t & 63;
    const int wr = wv >> 1, wc = wv & 1;

    // XCD-aware swizzle (nwg % 8 == 0 for all our grids)
    int nwg = gridDim.x * gridDim.y;
    int bid0 = blockIdx.y * gridDim.x + blockIdx.x;
    int qq = nwg >> 3;
    int swz = (bid0 & 7) * qq + (bid0 >> 3);
    const int tm = (swz / gridDim.x) * BM;
    const int bn = (swz % gridDim.x) * BN;

    const int kb = ln >> 4;          // 0..3
    const int lr = ln & 15;
    const int srow = ln >> 3;
    const int susw = (ln & 7) ^ srow;

    f32x4 acc[WM][WN];
    #pragma unroll
    for (int i = 0; i < WM; ++i)
        #pragma unroll
        for (int j = 0; j < WN; ++j) { f32x4 z = {0.f, 0.f, 0.f, 0.f}; acc[i][j] = z; }

    for (int k0 = 0; k0 < K; k0 += 64) {
        #pragma unroll
        for (int q = 0; q < BM / 32; ++q) {
            int seg = q * 4 + wv;
            int row = seg * 8 + srow;
            const _Float16* src = A + (size_t)(tm + row) * K + k0 + susw * 8;
            gload_lds16(src, (void*)(As + seg * 512));
        }
        #pragma unroll
        for (int q = 0; q < BN / 32; ++q) {
            int seg = q * 4 + wv;
            int row = seg * 8 + srow;
            const _Float16* src = B + (size_t)(bn + row) * K + k0 + susw * 8;
            gload_lds16(src, (void*)(Bs + seg * 512));
        }
        __syncthreads();

        #pragma unroll
        for (int ks = 0; ks < 2; ++ks) {
            half8 af[WM], bf[WN];
            #pragma unroll
            for (int mi = 0; mi < WM; ++mi) {
                int r = wr * (16 * WM) + mi * 16 + lr;
                af[mi] = *(const half8*)(As + r * 64 + (((ks * 4 + kb) ^ (r & 7)) << 3));
            }
            #pragma unroll
            for (int ni = 0; ni < WN; ++ni) {
                int r = wc * (16 * WN) + ni * 16 + lr;
                bf[ni] = *(const half8*)(Bs + r * 64 + (((ks * 4 + kb) ^ (r & 7)) << 3));
            }
            #pragma unroll
            for (int mi = 0; mi < WM; ++mi)
                #pragma unroll
                for (int ni = 0; ni < WN; ++ni)
                    acc[mi][ni] = __builtin_amdgcn_mfma_f32_16x16x32_f16(af[mi], bf[ni], acc[mi][ni], 0, 0, 0);
        }
        __syncthreads();
    }

    #pragma unroll
    for (int mi = 0; mi < WM; ++mi) {
        #pragma unroll
        for (int ni = 0; ni < WN; ++ni) {
            int col = bn + wc * (16 * WN) + ni * 16 + lr;
            if (col < Nc) {
                int row = tm + wr * (16 * WM) + mi * 16 + (ln >> 4) * 4;
                if (HOUT) {
                    _Float16* C = (_Float16*)Cout;
                    #pragma unroll
                    for (int r = 0; r < 4; ++r)
                        C[(size_t)(row + r) * ldc + col] = (_Float16)acc[mi][ni][r];
                    if (col >= DTCOL) {
                        #pragma unroll
                        for (int r = 0; r < 4; ++r)
                            dtraw[(size_t)(col - DTCOL) * ROWS + row + r] = acc[mi][ni][r];
                    }
                } else {
                    float* C = (float*)Cout;
                    #pragma unroll
                    for (int r = 0; r < 4; ++r)
                        C[(size_t)(row + r) * ldc + col] = acc[mi][ni][r];
                }
            }
        }
    }
}

// ---------------------------------------------------------------------------
// casts
// ---------------------------------------------------------------------------
__global__ __launch_bounds__(256) void cast_f16_kernel(const float* __restrict__ src,
                                                       _Float16* __restrict__ dst, int n8) {
    int i = blockIdx.x * 256 + threadIdx.x;
    if (i >= n8) return;
    float4 a = ((const float4*)src)[2 * i];
    float4 b = ((const float4*)src)[2 * i + 1];
    half8 h;
    h[0] = (_Float16)a.x; h[1] = (_Float16)a.y; h[2] = (_Float16)a.z; h[3] = (_Float16)a.w;
    h[4] = (_Float16)b.x; h[5] = (_Float16)b.y; h[6] = (_Float16)b.z; h[7] = (_Float16)b.w;
    ((half8*)dst)[i] = h;
}

__global__ __launch_bounds__(256) void cast_pad_f16_kernel(const float* __restrict__ src,
                                                           _Float16* __restrict__ dst,
                                                           int srcRows, int cols, int n8) {
    int i = blockIdx.x * 256 + threadIdx.x;
    if (i >= n8) return;
    int row = (i * 8) / cols;
    half8 h;
    if (row < srcRows) {
        float4 a = ((const float4*)src)[2 * i];
        float4 b = ((const float4*)src)[2 * i + 1];
        h[0] = (_Float16)a.x; h[1] = (_Float16)a.y; h[2] = (_Float16)a.z; h[3] = (_Float16)a.w;
        h[4] = (_Float16)b.x; h[5] = (_Float16)b.y; h[6] = (_Float16)b.z; h[7] = (_Float16)b.w;
    } else {
        #pragma unroll
        for (int q = 0; q < 8; ++q) h[q] = (_Float16)0.f;
    }
    ((half8*)dst)[i] = h;
}

// ---------------------------------------------------------------------------
// Conv + SiLU (f16 zx input), tiled with LDS transpose.
// ---------------------------------------------------------------------------
__global__ __launch_bounds__(256) void conv_silu_kernel(const _Float16* __restrict__ zx,
                                                        const float* __restrict__ conv_w,
                                                        const float* __restrict__ conv_b,
                                                        _Float16* __restrict__ xbc,
                                                        _Float16* __restrict__ xTg,
                                                        _Float16* __restrict__ BTg) {
    __shared__ float zs[67 * 64];
    __shared__ float os[64 * 65];
    const int bid = blockIdx.x;
    const int cg = bid % 36;
    const int bc = bid / 36;
    const int b = bc >> 3, cloc = bc & 7;
    const int c0 = cg * 64;
    const int t = threadIdx.x;

    const int cc = c0 + (t & 63);
    const float w0 = conv_w[cc * 4 + 0], w1 = conv_w[cc * 4 + 1];
    const float w2 = conv_w[cc * 4 + 2], w3 = conv_w[cc * 4 + 3];
    const float bias = conv_b[cc];

    for (int lt = 0; lt < 4; ++lt) {
        const int lbase = cloc * 256 + lt * 64;
        __syncthreads();
        for (int i = t; i < 67 * 64; i += 256) {
            int r = i >> 6, col = i & 63;
            int lseq = lbase - 3 + r;
            float v = 0.f;
            if (lseq >= 0)
                v = (float)zx[((size_t)(b * SEQ + lseq)) * DINPROJ + DSSM + c0 + col];
            zs[i] = v;
        }
        __syncthreads();
        {
            int c = t & 63;
            int w = t >> 6;
            #pragma unroll
            for (int j = 0; j < 16; ++j) {
                int l = w * 16 + j;
                float acc = bias + zs[(l + 0) * 64 + c] * w0 + zs[(l + 1) * 64 + c] * w1
                                 + zs[(l + 2) * 64 + c] * w2 + zs[(l + 3) * 64 + c] * w3;
                os[l * 65 + c] = acc / (1.f + expf(-acc));
            }
        }
        __syncthreads();
        {
            int l = t >> 2, cs = (t & 3) * 16;
            size_t m = (size_t)(b * SEQ + lbase + l);
            half8 h0, h1;
            #pragma unroll
            for (int i = 0; i < 8; ++i) h0[i] = (_Float16)os[l * 65 + cs + i];
            #pragma unroll
            for (int i = 0; i < 8; ++i) h1[i] = (_Float16)os[l * 65 + cs + 8 + i];
            _Float16* dst = xbc + m * CONVDIM + c0 + cs;
            *(half8*)dst = h0;
            *(half8*)(dst + 8) = h1;
        }
        if (c0 < CBASE) {
            int c = t >> 2, ls = (t & 3) * 16;
            int gc = c0 + c;
            half8 h0, h1;
            #pragma unroll
            for (int i = 0; i < 8; ++i) h0[i] = (_Float16)os[(ls + i) * 65 + c];
            #pragma unroll
            for (int i = 0; i < 8; ++i) h1[i] = (_Float16)os[(ls + 8 + i) * 65 + c];
            _Float16* dst;
            if (gc < DSSM)
                dst = xTg + ((size_t)bc * 2048 + gc) * 256 + lt * 64 + ls;
            else
                dst = BTg + ((size_t)bc * 128 + (gc - DSSM)) * 256 + lt * 64 + ls;
            *(half8*)dst = h0;
            *(half8*)(dst + 8) = h1;
        }
    }
}

// ---------------------------------------------------------------------------
// Parallel dt+cumsum: one block per (bc,h). 256 threads: coalesced load of
// the h-major dt_raw row, parallel softplus, LDS Hillis-Steele inclusive
// scan of dA. Outputs in [bc*32+h][l] layout (coalesced for all consumers).
// ---------------------------------------------------------------------------
__global__ __launch_bounds__(256) void dtcum_kernel(const float* __restrict__ dtraw,
                                                    const float* __restrict__ dt_bias,
                                                    const float* __restrict__ A_log,
                                                    float* __restrict__ dtT,
                                                    float* __restrict__ cumT) {
    __shared__ float sv[256];
    const int bid = blockIdx.x;          // bc*32 + h
    const int h = bid & 31, bc = bid >> 5;
    const int t = threadIdx.x;
    float v = dtraw[(size_t)h * ROWS + bc * 256 + t] + dt_bias[h];
    float d = (v > 20.f) ? v : log1pf(expf(v));
    float A = -expf(A_log[h]);
    dtT[(size_t)bid * 256 + t] = d;
    sv[t] = d * A;
    #pragma unroll
    for (int off = 1; off < 256; off <<= 1) {
        __syncthreads();
        float add = (t >= off) ? sv[t - off] : 0.f;
        __syncthreads();
        sv[t] += add;
    }
    __syncthreads();
    cumT[(size_t)bid * 256 + t] = sv[t];
}

// ---------------------------------------------------------------------------
// Chunk states via MFMA: S[p][n] = sum_l (coef[l]*x[l,p]) * B[l,n]
// ---------------------------------------------------------------------------
__global__ __launch_bounds__(256) void chunk_state_mfma(const _Float16* __restrict__ xTg,
                                                        const _Float16* __restrict__ BTg,
                                                        const float* __restrict__ dtT,
                                                        const float* __restrict__ cumT,
                                                        float* __restrict__ S) {
    int bid = blockIdx.x;
    int bc = bid >> 5;
    __shared__ _Float16 cxs[64 * 64];
    __shared__ _Float16 bts[128 * 64];
    __shared__ float coefL[256];
    const int t = threadIdx.x, w = t >> 6, ln = t & 63;
    const int lr = ln & 15, lg = ln >> 4;

    {
        float cl = cumT[(size_t)bid * 256 + 255];
        coefL[t] = expf(cl - cumT[(size_t)bid * 256 + t]) * dtT[(size_t)bid * 256 + t];
    }

    f32x4 sacc[4][2];
    #pragma unroll
    for (int pi = 0; pi < 4; ++pi)
        #pragma unroll
        for (int ni = 0; ni < 2; ++ni) { f32x4 z = {0.f,0.f,0.f,0.f}; sacc[pi][ni] = z; }

    const _Float16* xTh = xTg + (size_t)bid * 64 * 256;

    for (int kt = 0; kt < 4; ++kt) {
        __syncthreads();
        {
            int p = t >> 2, l0 = (t & 3) * 16;
            const _Float16* src = xTh + (size_t)p * 256 + kt * 64;
            #pragma unroll
            for (int q = 0; q < 2; ++q) {
                int c = l0 + q * 8;
                half8 hv = *(const half8*)(src + c);
                half8 ov;
                #pragma unroll
                for (int j = 0; j < 8; ++j)
                    ov[j] = (_Float16)((float)hv[j] * coefL[kt * 64 + c + j]);
                *(half8*)(cxs + p * 64 + (c ^ ((p & 7) << 3))) = ov;
            }
        }
        #pragma unroll
        for (int q = 0; q < 4; ++q) {
            int seg = w * 4 + q;
            int r = seg * 8 + (ln >> 3);
            int csw = 8 * ((ln & 7) ^ (r & 7));
            const _Float16* src = BTg + ((size_t)bc * 128 + r) * 256 + kt * 64 + csw;
            gload_lds16(src, (void*)(bts + seg * 512));
        }
        __syncthreads();
        #pragma unroll
        for (int kk = 0; kk < 2; ++kk) {
            int c0 = kk * 32 + lg * 8;
            half8 ax[4], bx[2];
            #pragma unroll
            for (int pi = 0; pi < 4; ++pi) {
                int r = pi * 16 + lr;
                ax[pi] = *(const half8*)(cxs + r * 64 + (c0 ^ ((r & 7) << 3)));
            }
            #pragma unroll
            for (int ni = 0; ni < 2; ++ni) {
                int r = w * 32 + ni * 16 + lr;
                bx[ni] = *(const half8*)(bts + r * 64 + (c0 ^ ((r & 7) << 3)));
            }
            #pragma unroll
            for (int pi = 0; pi < 4; ++pi)
                #pragma unroll
                for (int ni = 0; ni < 2; ++ni)
                    sacc[pi][ni] = __builtin_amdgcn_mfma_f32_16x16x32_f16(ax[pi], bx[ni], sacc[pi][ni], 0, 0, 0);
        }
    }
    float* sb = S + (size_t)bid * (DHEAD * DSTATE);
    #pragma unroll
    for (int pi = 0; pi < 4; ++pi)
        #pragma unroll
        for (int ni = 0; ni < 2; ++ni)
            #pragma unroll
            for (int r = 0; r < 4; ++r) {
                int p = pi * 16 + lg * 4 + r;
                int n = w * 32 + ni * 16 + lr;
                sb[p * 128 + n] = sacc[pi][ni][r];
            }
}

// ---------------------------------------------------------------------------
// Inter-chunk scan; S[c] <- state ENTERING chunk c.
// ---------------------------------------------------------------------------
__global__ __launch_bounds__(256) void scan_kernel(const float* __restrict__ cumT,
                                                   float* __restrict__ S) {
    int bid = blockIdx.x;            // b*32 + h
    int h = bid & 31, b = bid >> 5;
    int t = threadIdx.x;
    float carry[32];
    #pragma unroll
    for (int i = 0; i < 32; ++i) carry[i] = 0.f;
    for (int c = 0; c < NCHUNK; ++c) {
        int bc = b * NCHUNK + c;
        float decay = expf(cumT[((size_t)(bc * 32 + h)) * 256 + 255]);
        size_t base = ((size_t)(bc * NHEADS + h)) * (DHEAD * DSTATE);
        #pragma unroll
        for (int i = 0; i < 32; ++i) {
            size_t idx = base + t + i * 256;
            float s = S[idx];
            float nw = carry[i] * decay + s;
            S[idx] = carry[i];
            carry[i] = nw;
        }
    }
}

// ---------------------------------------------------------------------------
// Y via MFMA v2
// ---------------------------------------------------------------------------
__global__ __launch_bounds__(256, 2) void y_mfma(const _Float16* __restrict__ xbc,
                                                 const _Float16* __restrict__ xTg,
                                                 const float* __restrict__ dtT,
                                                 const float* __restrict__ cumT,
                                                 const float* __restrict__ Sprev,
                                                 const float* __restrict__ Dp,
                                                 float* __restrict__ y) {
    int bid = blockIdx.x;
    int h = bid & 31, bc = bid >> 5;
    __shared__ _Float16 Bs2[2][64 * 128];
    __shared__ _Float16 PwF[4 * 64 * 64];
    __shared__ float cumL[256], dtL[256];
    const int t = threadIdx.x, w = t >> 6, ln = t & 63;
    const int lr = ln & 15, lg = ln >> 4;

    {
        cumL[t] = cumT[(size_t)bid * 256 + t];
        dtL[t]  = dtT[(size_t)bid * 256 + t];
    }
    {
        const float* sp = Sprev + (size_t)bid * (DHEAD * DSTATE);
        int r = t >> 2, cb = (t & 3) * 32;
        #pragma unroll
        for (int q = 0; q < 4; ++q) {
            int c = cb + q * 8;
            float4 f0 = *(const float4*)(sp + r * 128 + c);
            float4 f1 = *(const float4*)(sp + r * 128 + c + 4);
            half8 hv;
            hv[0]=(_Float16)f0.x; hv[1]=(_Float16)f0.y; hv[2]=(_Float16)f0.z; hv[3]=(_Float16)f0.w;
            hv[4]=(_Float16)f1.x; hv[5]=(_Float16)f1.y; hv[6]=(_Float16)f1.z; hv[7]=(_Float16)f1.w;
            *(half8*)(PwF + r * 128 + (c ^ ((r & 7) << 3))) = hv;
        }
    }
    {
        #pragma unroll
        for (int q = 0; q < 4; ++q) {
            int seg = w * 4 + q;
            int r = seg * 4 + lg;
            int csw = 8 * (lr ^ (r & 7));
            const _Float16* src = xbc + ((size_t)(bc * 256 + r)) * CONVDIM + DSSM + csw;
            gload_lds16(src, (void*)(Bs2[0] + seg * 512));
        }
    }
    half8 ca[4][4];
    {
        const _Float16* cb = xbc + ((size_t)(bc * 256 + w * 64)) * CONVDIM + CBASE;
        #pragma unroll
        for (int mi = 0; mi < 4; ++mi)
            #pragma unroll
            for (int kk = 0; kk < 4; ++kk)
                ca[mi][kk] = *(const half8*)(cb + (size_t)(mi * 16 + lr) * CONVDIM + kk * 32 + lg * 8);
    }
    __syncthreads();

    f32x4 yacc[4][4];
    #pragma unroll
    for (int i = 0; i < 4; ++i)
        #pragma unroll
        for (int j = 0; j < 4; ++j) { f32x4 z = {0.f,0.f,0.f,0.f}; yacc[i][j] = z; }

    #pragma unroll
    for (int kk = 0; kk < 4; ++kk) {
        int co = kk * 32 + lg * 8;
        #pragma unroll
        for (int pi = 0; pi < 4; ++pi) {
            int r = pi * 16 + lr;
            half8 pb = *(const half8*)(PwF + r * 128 + (co ^ ((r & 7) << 3)));
            #pragma unroll
            for (int mi = 0; mi < 4; ++mi)
                yacc[mi][pi] = __builtin_amdgcn_mfma_f32_16x16x32_f16(ca[mi][kk], pb, yacc[mi][pi], 0, 0, 0);
        }
    }
    #pragma unroll
    for (int mi = 0; mi < 4; ++mi)
        #pragma unroll
        for (int r = 0; r < 4; ++r) {
            float e = expf(cumL[w * 64 + mi * 16 + lg * 4 + r]);
            #pragma unroll
            for (int pi = 0; pi < 4; ++pi) yacc[mi][pi][r] *= e;
        }
    float c0 = cumL[w * 64];
    float el[4];
    #pragma unroll
    for (int mi = 0; mi < 4; ++mi) el[mi] = expf(cumL[w * 64 + mi * 16 + lr] - c0);
    float Dv = Dp[h];

    __syncthreads();

    _Float16* pwb = PwF + w * 4096;
    for (int st = 0; st < 4; ++st) {
        if (st < 3) {
            #pragma unroll
            for (int q = 0; q < 4; ++q) {
                int seg = w * 4 + q;
                int r = seg * 4 + lg;
                int csw = 8 * (lr ^ (r & 7));
                const _Float16* src = xbc + ((size_t)(bc * 256 + (st + 1) * 64 + r)) * CONVDIM + DSSM + csw;
                gload_lds16(src, (void*)(Bs2[(st + 1) & 1] + seg * 512));
            }
        }
        if (st <= w) {
            const _Float16* bsc = Bs2[st & 1];
            half8 xb[4][2];
            #pragma unroll
            for (int pi = 0; pi < 4; ++pi)
                #pragma unroll
                for (int k2 = 0; k2 < 2; ++k2)
                    xb[pi][k2] = *(const half8*)(xTg + ((size_t)bid * 64 + pi * 16 + lr) * 256
                                                 + st * 64 + k2 * 32 + lg * 8);
            #pragma unroll
            for (int si = 0; si < 4; ++si) {
                f32x4 ps[4];
                #pragma unroll
                for (int mi = 0; mi < 4; ++mi) { f32x4 z = {0.f,0.f,0.f,0.f}; ps[mi] = z; }
                int r = si * 16 + lr;
                #pragma unroll
                for (int kk = 0; kk < 4; ++kk) {
                    int co = kk * 32 + lg * 8;
                    half8 bb = *(const half8*)(bsc + r * 128 + (co ^ ((r & 7) << 3)));
                    #pragma unroll
                    for (int mi = 0; mi < 4; ++mi)
                        ps[mi] = __builtin_amdgcn_mfma_f32_16x16x32_f16(bb, ca[mi][kk], ps[mi], 0, 0, 0);
                }
                if (st < w) {
                    float fs[4];
                    #pragma unroll
                    for (int rr = 0; rr < 4; ++rr) {
                        int sg = st * 64 + si * 16 + lg * 4 + rr;
                        fs[rr] = expf(c0 - cumL[sg]) * dtL[sg];
                    }
                    #pragma unroll
                    for (int mi = 0; mi < 4; ++mi) {
                        half4 hv;
                        #pragma unroll
                        for (int rr = 0; rr < 4; ++rr)
                            hv[rr] = (_Float16)(ps[mi][rr] * el[mi] * fs[rr]);
                        *(half4*)(pwb + (mi * 16 + lr) * 64 + ((si * 16 + lg * 4) ^ (8 * (lr & 7)))) = hv;
                    }
                } else {
                    #pragma unroll
                    for (int mi = 0; mi < 4; ++mi) {
                        int lloc = mi * 16 + lr;
                        float cl = cumL[w * 64 + lloc];
                        half4 hv;
                        #pragma unroll
                        for (int rr = 0; rr < 4; ++rr) {
                            int sl = si * 16 + lg * 4 + rr;
                            float v = 0.f;
                            if (sl <= lloc) {
                                int sg = w * 64 + sl;
                                v = ps[mi][rr] * expf(cl - cumL[sg]) * dtL[sg];
                                if (sl == lloc) v += Dv;
                            }
                            hv[rr] = (_Float16)v;
                        }
                        *(half4*)(pwb + (mi * 16 + lr) * 64 + ((si * 16 + lg * 4) ^ (8 * (lr & 7)))) = hv;
                    }
                }
            }
            #pragma unroll
            for (int k2 = 0; k2 < 2; ++k2) {
                int co = k2 * 32 + lg * 8;
                half8 pa[4];
                #pragma unroll
                for (int mi = 0; mi < 4; ++mi) {
                    int r = mi * 16 + lr;
                    pa[mi] = *(const half8*)(pwb + r * 64 + (co ^ (8 * (lr & 7))));
                }
                #pragma unroll
                for (int pi = 0; pi < 4; ++pi)
                    #pragma unroll
                    for (int mi = 0; mi < 4; ++mi)
                        yacc[mi][pi] = __builtin_amdgcn_mfma_f32_16x16x32_f16(pa[mi], xb[pi][k2], yacc[mi][pi], 0, 0, 0);
            }
        }
        __syncthreads();
    }

    #pragma unroll
    for (int mi = 0; mi < 4; ++mi) {
        #pragma unroll
        for (int r = 0; r < 4; ++r) {
            int l = w * 64 + mi * 16 + lg * 4 + r;
            size_t row = (size_t)bc * 256 + l;
            #pragma unroll
            for (int pi = 0; pi < 4; ++pi)
                y[row * DSSM + h * 64 + pi * 16 + lr] = yacc[mi][pi][r];
        }
    }
}

// ---------------------------------------------------------------------------
// Gated RMSNorm (f16 z input) -> f16 output for out_proj MFMA
// ---------------------------------------------------------------------------
__global__ __launch_bounds__(256) void norm_kernel(const float* __restrict__ y,
                                                   const _Float16* __restrict__ zx,
                                                   const float* __restrict__ norm_w,
                                                   _Float16* __restrict__ outh) {
    int m = blockIdx.x;
    int t = threadIdx.x;
    const float* yrow = y + (size_t)m * DSSM;
    const _Float16* zrow = zx + (size_t)m * DINPROJ;
    float yg[8];
    float ss = 0.f;
    half8 zv = *(const half8*)(zrow + t * 8);
    float4 yv0 = *(const float4*)(yrow + t * 8);
    float4 yv1 = *(const float4*)(yrow + t * 8 + 4);
    float yvals[8] = {yv0.x, yv0.y, yv0.z, yv0.w, yv1.x, yv1.y, yv1.z, yv1.w};
    #pragma unroll
    for (int i = 0; i < 8; ++i) {
        float z = (float)zv[i];
        float sz = z / (1.f + expf(-z));
        float g = yvals[i] * sz;
        yg[i] = g;
        ss += g * g;
    }
    #pragma unroll
    for (int off = 32; off > 0; off >>= 1) ss += __shfl_xor(ss, off, 64);
    __shared__ float red[4];
    if ((t & 63) == 0) red[t >> 6] = ss;
    __syncthreads();
    float tot = red[0] + red[1] + red[2] + red[3];
    float inv = rsqrtf(tot / (float)DSSM + EPSF);
    half8 h;
    #pragma unroll
    for (int q = 0; q < 8; ++q)
        h[q] = (_Float16)(yg[q] * inv * norm_w[t*8 + q]);
    *(half8*)(outh + (size_t)m * DSSM + t * 8) = h;
}

// ---------------------------------------------------------------------------
extern "C" void kernel_launch(void* const* d_in, const int* in_sizes, int n_in,
                              void* d_out, int out_size, void* d_ws, size_t ws_size,
                              hipStream_t stream) {
    (void)in_sizes; (void)n_in; (void)out_size; (void)ws_size;
    const float* u       = (const float*)d_in[0];
    const float* W_in    = (const float*)d_in[1];
    const float* conv_w  = (const float*)d_in[2];
    const float* conv_b  = (const float*)d_in[3];
    const float* dt_bias = (const float*)d_in[4];
    const float* A_log   = (const float*)d_in[5];
    const float* Dp      = (const float*)d_in[6];
    const float* norm_w  = (const float*)d_in[7];
    const float* W_out   = (const float*)d_in[8];
    float* out = (float*)d_out;

    // workspace layout: f32 region first, then f16 region
    float* dtraw = (float*)d_ws;                       // NHEADS*ROWS (h-major)
    float* dtb   = dtraw + (size_t)ROWS * NHEADS;      // [(bc*32+h)*256+l]
    float* cum   = dtb   + (size_t)ROWS * NHEADS;
    float* Sbuf  = cum   + (size_t)ROWS * NHEADS;      // 512*64*128
    float* yb    = Sbuf  + (size_t)NBC * NHEADS * DHEAD * DSTATE;  // ROWS*DSSM
    _Float16* zxh   = (_Float16*)(yb + (size_t)ROWS * DSSM);       // ROWS*DINPROJ
    _Float16* xbc_h = zxh   + (size_t)ROWS * DINPROJ;              // ROWS*CONVDIM
    _Float16* xTg   = xbc_h + (size_t)ROWS * CONVDIM;              // 512*64*256
    _Float16* BTg   = xTg   + (size_t)NBC * NHEADS * 64 * 256;     // 16*128*256
    _Float16* uh    = BTg   + (size_t)NBC * 128 * 256;
    _Float16* Wih   = uh    + (size_t)ROWS * DMODEL;
    _Float16* Wouth = Wih   + (size_t)NPAD * DMODEL;
    _Float16* ybh   = Wouth + (size_t)DMODEL * DSSM;

    // casts
    cast_f16_kernel<<<(ROWS * DMODEL / 8 + 255) / 256, 256, 0, stream>>>(u, uh, ROWS * DMODEL / 8);
    cast_pad_f16_kernel<<<(NPAD * DMODEL / 8 + 255) / 256, 256, 0, stream>>>(
        W_in, Wih, DINPROJ, DMODEL, NPAD * DMODEL / 8);
    cast_f16_kernel<<<(DMODEL * DSSM / 8 + 255) / 256, 256, 0, stream>>>(W_out, Wouth, DMODEL * DSSM / 8);

    // 1. in_proj -> f16 zx (+ f32 h-major dt_raw side-channel)
    gemm_f16<4, 4, true><<<dim3(NPAD / 128, ROWS / 128), 256, 0, stream>>>(
        uh, Wih, (void*)zxh, dtraw, DMODEL, DINPROJ, DINPROJ);
    // 2. conv + silu -> f16 xbc + transposed copies
    conv_silu_kernel<<<NBC * 36, 256, 0, stream>>>(
        zxh, conv_w, conv_b, xbc_h, xTg, BTg);
    // 3. dt + cumsum (parallel block scan)
    dtcum_kernel<<<NBC * NHEADS, 256, 0, stream>>>(dtraw, dt_bias, A_log, dtb, cum);
    // 4. chunk states (MFMA)
    chunk_state_mfma<<<NBC * NHEADS, 256, 0, stream>>>(xTg, BTg, dtb, cum, Sbuf);
    // 5. inter-chunk scan
    scan_kernel<<<BATCH * NHEADS, 256, 0, stream>>>(cum, Sbuf);
    // 6. Y (MFMA v2)
    y_mfma<<<NBC * NHEADS, 256, 0, stream>>>(xbc_h, xTg, dtb, cum, Sbuf, Dp, yb);
    // 7. gated RMSNorm -> f16
    norm_kernel<<<ROWS, 256, 0, stream>>>(yb, zxh, norm_w, ybh);
    // 8. out_proj (f32 out)
    gemm_f16<4, 2, false><<<dim3(DMODEL / 64, ROWS / 128), 256, 0, stream>>>(
        ybh, Wouth, (void*)out, nullptr, DSSM, DMODEL, DMODEL);
}

// Round 8
// 289.330 us; speedup vs baseline: 1.5165x; 1.0371x over previous
//
#include <hip/hip_runtime.h>
#include <hip/hip_bf16.h>
#include <math.h>
#include <stdint.h>

// Problem constants
#define BATCH    2
#define SEQ      2048
#define DMODEL   1024
#define DSSM     2048
#define NHEADS   32
#define DHEAD    64
#define DSTATE   128
#define CONVDIM  2304     // DSSM + 2*DSTATE
#define DINPROJ  4384     // 2*2048 + 2*128 + 32
#define NPAD     4480     // DINPROJ padded to multiple of 128
#define CHUNK    256
#define NCHUNK   8
#define ROWS     (BATCH*SEQ)          // 4096
#define NBC      (BATCH*NCHUNK)       // 16
#define EPSF     1e-5f
#define CBASE    (DSSM + DSTATE)      // 2176, C columns in xbc
#define DTCOL    (DSSM + CONVDIM)     // 4352, dt_raw columns start

typedef _Float16 half8 __attribute__((ext_vector_type(8)));
typedef _Float16 half4 __attribute__((ext_vector_type(4)));
typedef float f32x4 __attribute__((ext_vector_type(4)));

// global_load_lds: 16B per lane, LDS dest = wave-uniform base + lane*16
static __device__ __forceinline__ void gload_lds16(const void* g, void* l) {
    __builtin_amdgcn_global_load_lds(
        (const __attribute__((address_space(1))) uint32_t*)g,
        (__attribute__((address_space(3))) uint32_t*)l, 16, 0, 0);
}

// ---------------------------------------------------------------------------
// MFMA GEMM (f16 in): C[M,N] = A[M,K] * B[N,K]^T.  BK=64, XOR-swizzled LDS,
// XCD-aware block swizzle, 2-phase pipelined (double-buffered LDS, prefetch
// next K-tile before compute, setprio around MFMA cluster).
// HOUT: store f16 + f32 h-major dt_raw side-channel. !HOUT: store f32.
// ---------------------------------------------------------------------------
template<int WM, int WN, bool HOUT>
__global__ __launch_bounds__(256) void gemm_f16(const _Float16* __restrict__ A,
                                                const _Float16* __restrict__ B,
                                                void* __restrict__ Cout,
                                                float* __restrict__ dtraw,
                                                int K, int ldc, int Nc) {
    constexpr int BM = 32 * WM;
    constexpr int BN = 32 * WN;
    __shared__ _Float16 As[2][BM * 64];
    __shared__ _Float16 Bs[2][BN * 64];
    const int t  = threadIdx.x;
    const int wv = t >> 6;
    const int ln = t & 63;
    const int wr = wv >> 1, wc = wv & 1;

    // XCD-aware swizzle (nwg % 8 == 0 for all our grids)
    int nwg = gridDim.x * gridDim.y;
    int bid0 = blockIdx.y * gridDim.x + blockIdx.x;
    int qq = nwg >> 3;
    int swz = (bid0 & 7) * qq + (bid0 >> 3);
    const int tm = (swz / gridDim.x) * BM;
    const int bn = (swz % gridDim.x) * BN;

    const int kb = ln >> 4;          // 0..3
    const int lr = ln & 15;
    const int srow = ln >> 3;
    const int susw = (ln & 7) ^ srow;

    f32x4 acc[WM][WN];
    #pragma unroll
    for (int i = 0; i < WM; ++i)
        #pragma unroll
        for (int j = 0; j < WN; ++j) { f32x4 z = {0.f, 0.f, 0.f, 0.f}; acc[i][j] = z; }

    auto stage = [&](int buf, int k0) {
        #pragma unroll
        for (int q = 0; q < BM / 32; ++q) {
            int seg = q * 4 + wv;
            int row = seg * 8 + srow;
            const _Float16* src = A + (size_t)(tm + row) * K + k0 + susw * 8;
            gload_lds16(src, (void*)(As[buf] + seg * 512));
        }
        #pragma unroll
        for (int q = 0; q < BN / 32; ++q) {
            int seg = q * 4 + wv;
            int row = seg * 8 + srow;
            const _Float16* src = B + (size_t)(bn + row) * K + k0 + susw * 8;
            gload_lds16(src, (void*)(Bs[buf] + seg * 512));
        }
    };

    stage(0, 0);
    __syncthreads();
    int cur = 0;

    for (int k0 = 0; k0 < K; k0 += 64) {
        if (k0 + 64 < K) stage(cur ^ 1, k0 + 64);   // prefetch next tile

        __builtin_amdgcn_s_setprio(1);
        #pragma unroll
        for (int ks = 0; ks < 2; ++ks) {
            half8 af[WM], bf[WN];
            #pragma unroll
            for (int mi = 0; mi < WM; ++mi) {
                int r = wr * (16 * WM) + mi * 16 + lr;
                af[mi] = *(const half8*)(As[cur] + r * 64 + (((ks * 4 + kb) ^ (r & 7)) << 3));
            }
            #pragma unroll
            for (int ni = 0; ni < WN; ++ni) {
                int r = wc * (16 * WN) + ni * 16 + lr;
                bf[ni] = *(const half8*)(Bs[cur] + r * 64 + (((ks * 4 + kb) ^ (r & 7)) << 3));
            }
            #pragma unroll
            for (int mi = 0; mi < WM; ++mi)
                #pragma unroll
                for (int ni = 0; ni < WN; ++ni)
                    acc[mi][ni] = __builtin_amdgcn_mfma_f32_16x16x32_f16(af[mi], bf[ni], acc[mi][ni], 0, 0, 0);
        }
        __builtin_amdgcn_s_setprio(0);
        __syncthreads();   // drains prefetch vmcnt (mostly landed under compute)
        cur ^= 1;
    }

    #pragma unroll
    for (int mi = 0; mi < WM; ++mi) {
        #pragma unroll
        for (int ni = 0; ni < WN; ++ni) {
            int col = bn + wc * (16 * WN) + ni * 16 + lr;
            if (col < Nc) {
                int row = tm + wr * (16 * WM) + mi * 16 + (ln >> 4) * 4;
                if (HOUT) {
                    _Float16* C = (_Float16*)Cout;
                    #pragma unroll
                    for (int r = 0; r < 4; ++r)
                        C[(size_t)(row + r) * ldc + col] = (_Float16)acc[mi][ni][r];
                    if (col >= DTCOL) {
                        #pragma unroll
                        for (int r = 0; r < 4; ++r)
                            dtraw[(size_t)(col - DTCOL) * ROWS + row + r] = acc[mi][ni][r];
                    }
                } else {
                    float* C = (float*)Cout;
                    #pragma unroll
                    for (int r = 0; r < 4; ++r)
                        C[(size_t)(row + r) * ldc + col] = acc[mi][ni][r];
                }
            }
        }
    }
}

// ---------------------------------------------------------------------------
// casts
// ---------------------------------------------------------------------------
__global__ __launch_bounds__(256) void cast_f16_kernel(const float* __restrict__ src,
                                                       _Float16* __restrict__ dst, int n8) {
    int i = blockIdx.x * 256 + threadIdx.x;
    if (i >= n8) return;
    float4 a = ((const float4*)src)[2 * i];
    float4 b = ((const float4*)src)[2 * i + 1];
    half8 h;
    h[0] = (_Float16)a.x; h[1] = (_Float16)a.y; h[2] = (_Float16)a.z; h[3] = (_Float16)a.w;
    h[4] = (_Float16)b.x; h[5] = (_Float16)b.y; h[6] = (_Float16)b.z; h[7] = (_Float16)b.w;
    ((half8*)dst)[i] = h;
}

__global__ __launch_bounds__(256) void cast_pad_f16_kernel(const float* __restrict__ src,
                                                           _Float16* __restrict__ dst,
                                                           int srcRows, int cols, int n8) {
    int i = blockIdx.x * 256 + threadIdx.x;
    if (i >= n8) return;
    int row = (i * 8) / cols;
    half8 h;
    if (row < srcRows) {
        float4 a = ((const float4*)src)[2 * i];
        float4 b = ((const float4*)src)[2 * i + 1];
        h[0] = (_Float16)a.x; h[1] = (_Float16)a.y; h[2] = (_Float16)a.z; h[3] = (_Float16)a.w;
        h[4] = (_Float16)b.x; h[5] = (_Float16)b.y; h[6] = (_Float16)b.z; h[7] = (_Float16)b.w;
    } else {
        #pragma unroll
        for (int q = 0; q < 8; ++q) h[q] = (_Float16)0.f;
    }
    ((half8*)dst)[i] = h;
}

// ---------------------------------------------------------------------------
// Conv + SiLU (f16 zx input), tiled with LDS transpose.
// ---------------------------------------------------------------------------
__global__ __launch_bounds__(256) void conv_silu_kernel(const _Float16* __restrict__ zx,
                                                        const float* __restrict__ conv_w,
                                                        const float* __restrict__ conv_b,
                                                        _Float16* __restrict__ xbc,
                                                        _Float16* __restrict__ xTg,
                                                        _Float16* __restrict__ BTg) {
    __shared__ float zs[67 * 64];
    __shared__ float os[64 * 65];
    const int bid = blockIdx.x;
    const int cg = bid % 36;
    const int bc = bid / 36;
    const int b = bc >> 3, cloc = bc & 7;
    const int c0 = cg * 64;
    const int t = threadIdx.x;

    const int cc = c0 + (t & 63);
    const float w0 = conv_w[cc * 4 + 0], w1 = conv_w[cc * 4 + 1];
    const float w2 = conv_w[cc * 4 + 2], w3 = conv_w[cc * 4 + 3];
    const float bias = conv_b[cc];

    for (int lt = 0; lt < 4; ++lt) {
        const int lbase = cloc * 256 + lt * 64;
        __syncthreads();
        for (int i = t; i < 67 * 64; i += 256) {
            int r = i >> 6, col = i & 63;
            int lseq = lbase - 3 + r;
            float v = 0.f;
            if (lseq >= 0)
                v = (float)zx[((size_t)(b * SEQ + lseq)) * DINPROJ + DSSM + c0 + col];
            zs[i] = v;
        }
        __syncthreads();
        {
            int c = t & 63;
            int w = t >> 6;
            #pragma unroll
            for (int j = 0; j < 16; ++j) {
                int l = w * 16 + j;
                float acc = bias + zs[(l + 0) * 64 + c] * w0 + zs[(l + 1) * 64 + c] * w1
                                 + zs[(l + 2) * 64 + c] * w2 + zs[(l + 3) * 64 + c] * w3;
                os[l * 65 + c] = acc / (1.f + expf(-acc));
            }
        }
        __syncthreads();
        {
            int l = t >> 2, cs = (t & 3) * 16;
            size_t m = (size_t)(b * SEQ + lbase + l);
            half8 h0, h1;
            #pragma unroll
            for (int i = 0; i < 8; ++i) h0[i] = (_Float16)os[l * 65 + cs + i];
            #pragma unroll
            for (int i = 0; i < 8; ++i) h1[i] = (_Float16)os[l * 65 + cs + 8 + i];
            _Float16* dst = xbc + m * CONVDIM + c0 + cs;
            *(half8*)dst = h0;
            *(half8*)(dst + 8) = h1;
        }
        if (c0 < CBASE) {
            int c = t >> 2, ls = (t & 3) * 16;
            int gc = c0 + c;
            half8 h0, h1;
            #pragma unroll
            for (int i = 0; i < 8; ++i) h0[i] = (_Float16)os[(ls + i) * 65 + c];
            #pragma unroll
            for (int i = 0; i < 8; ++i) h1[i] = (_Float16)os[(ls + 8 + i) * 65 + c];
            _Float16* dst;
            if (gc < DSSM)
                dst = xTg + ((size_t)bc * 2048 + gc) * 256 + lt * 64 + ls;
            else
                dst = BTg + ((size_t)bc * 128 + (gc - DSSM)) * 256 + lt * 64 + ls;
            *(half8*)dst = h0;
            *(half8*)(dst + 8) = h1;
        }
    }
}

// ---------------------------------------------------------------------------
// Parallel dt+cumsum: one block per (bc,h).
// ---------------------------------------------------------------------------
__global__ __launch_bounds__(256) void dtcum_kernel(const float* __restrict__ dtraw,
                                                    const float* __restrict__ dt_bias,
                                                    const float* __restrict__ A_log,
                                                    float* __restrict__ dtT,
                                                    float* __restrict__ cumT) {
    __shared__ float sv[256];
    const int bid = blockIdx.x;          // bc*32 + h
    const int h = bid & 31, bc = bid >> 5;
    const int t = threadIdx.x;
    float v = dtraw[(size_t)h * ROWS + bc * 256 + t] + dt_bias[h];
    float d = (v > 20.f) ? v : log1pf(expf(v));
    float A = -expf(A_log[h]);
    dtT[(size_t)bid * 256 + t] = d;
    sv[t] = d * A;
    #pragma unroll
    for (int off = 1; off < 256; off <<= 1) {
        __syncthreads();
        float add = (t >= off) ? sv[t - off] : 0.f;
        __syncthreads();
        sv[t] += add;
    }
    __syncthreads();
    cumT[(size_t)bid * 256 + t] = sv[t];
}

// ---------------------------------------------------------------------------
// Chunk states via MFMA: S[p][n] = sum_l (coef[l]*x[l,p]) * B[l,n]
// ---------------------------------------------------------------------------
__global__ __launch_bounds__(256) void chunk_state_mfma(const _Float16* __restrict__ xTg,
                                                        const _Float16* __restrict__ BTg,
                                                        const float* __restrict__ dtT,
                                                        const float* __restrict__ cumT,
                                                        float* __restrict__ S) {
    int bid = blockIdx.x;
    int bc = bid >> 5;
    __shared__ _Float16 cxs[64 * 64];
    __shared__ _Float16 bts[128 * 64];
    __shared__ float coefL[256];
    const int t = threadIdx.x, w = t >> 6, ln = t & 63;
    const int lr = ln & 15, lg = ln >> 4;

    {
        float cl = cumT[(size_t)bid * 256 + 255];
        coefL[t] = expf(cl - cumT[(size_t)bid * 256 + t]) * dtT[(size_t)bid * 256 + t];
    }

    f32x4 sacc[4][2];
    #pragma unroll
    for (int pi = 0; pi < 4; ++pi)
        #pragma unroll
        for (int ni = 0; ni < 2; ++ni) { f32x4 z = {0.f,0.f,0.f,0.f}; sacc[pi][ni] = z; }

    const _Float16* xTh = xTg + (size_t)bid * 64 * 256;

    for (int kt = 0; kt < 4; ++kt) {
        __syncthreads();
        {
            int p = t >> 2, l0 = (t & 3) * 16;
            const _Float16* src = xTh + (size_t)p * 256 + kt * 64;
            #pragma unroll
            for (int q = 0; q < 2; ++q) {
                int c = l0 + q * 8;
                half8 hv = *(const half8*)(src + c);
                half8 ov;
                #pragma unroll
                for (int j = 0; j < 8; ++j)
                    ov[j] = (_Float16)((float)hv[j] * coefL[kt * 64 + c + j]);
                *(half8*)(cxs + p * 64 + (c ^ ((p & 7) << 3))) = ov;
            }
        }
        #pragma unroll
        for (int q = 0; q < 4; ++q) {
            int seg = w * 4 + q;
            int r = seg * 8 + (ln >> 3);
            int csw = 8 * ((ln & 7) ^ (r & 7));
            const _Float16* src = BTg + ((size_t)bc * 128 + r) * 256 + kt * 64 + csw;
            gload_lds16(src, (void*)(bts + seg * 512));
        }
        __syncthreads();
        #pragma unroll
        for (int kk = 0; kk < 2; ++kk) {
            int c0 = kk * 32 + lg * 8;
            half8 ax[4], bx[2];
            #pragma unroll
            for (int pi = 0; pi < 4; ++pi) {
                int r = pi * 16 + lr;
                ax[pi] = *(const half8*)(cxs + r * 64 + (c0 ^ ((r & 7) << 3)));
            }
            #pragma unroll
            for (int ni = 0; ni < 2; ++ni) {
                int r = w * 32 + ni * 16 + lr;
                bx[ni] = *(const half8*)(bts + r * 64 + (c0 ^ ((r & 7) << 3)));
            }
            #pragma unroll
            for (int pi = 0; pi < 4; ++pi)
                #pragma unroll
                for (int ni = 0; ni < 2; ++ni)
                    sacc[pi][ni] = __builtin_amdgcn_mfma_f32_16x16x32_f16(ax[pi], bx[ni], sacc[pi][ni], 0, 0, 0);
        }
    }
    float* sb = S + (size_t)bid * (DHEAD * DSTATE);
    #pragma unroll
    for (int pi = 0; pi < 4; ++pi)
        #pragma unroll
        for (int ni = 0; ni < 2; ++ni)
            #pragma unroll
            for (int r = 0; r < 4; ++r) {
                int p = pi * 16 + lg * 4 + r;
                int n = w * 32 + ni * 16 + lr;
                sb[p * 128 + n] = sacc[pi][ni][r];
            }
}

// ---------------------------------------------------------------------------
// Inter-chunk scan; S[c] <- state ENTERING chunk c.  512 blocks:
// bid = (b*32+h)*8 + part, each block owns 1024 of the 8192 state elems.
// ---------------------------------------------------------------------------
__global__ __launch_bounds__(256) void scan_kernel(const float* __restrict__ cumT,
                                                   float* __restrict__ S) {
    int bid = blockIdx.x;
    int part = bid & 7;
    int bh = bid >> 3;               // b*32 + h
    int h = bh & 31, b = bh >> 5;
    int t = threadIdx.x;
    float carry[4];
    #pragma unroll
    for (int i = 0; i < 4; ++i) carry[i] = 0.f;
    for (int c = 0; c < NCHUNK; ++c) {
        int bc = b * NCHUNK + c;
        float decay = expf(cumT[((size_t)(bc * 32 + h)) * 256 + 255]);
        size_t base = ((size_t)(bc * 32 + h)) * (DHEAD * DSTATE) + part * 1024;
        #pragma unroll
        for (int i = 0; i < 4; ++i) {
            size_t idx = base + t + i * 256;
            float s = S[idx];
            float nw = carry[i] * decay + s;
            S[idx] = carry[i];
            carry[i] = nw;
        }
    }
}

// ---------------------------------------------------------------------------
// Y via MFMA v2 (f16 output)
// ---------------------------------------------------------------------------
__global__ __launch_bounds__(256, 2) void y_mfma(const _Float16* __restrict__ xbc,
                                                 const _Float16* __restrict__ xTg,
                                                 const float* __restrict__ dtT,
                                                 const float* __restrict__ cumT,
                                                 const float* __restrict__ Sprev,
                                                 const float* __restrict__ Dp,
                                                 _Float16* __restrict__ y) {
    int bid = blockIdx.x;
    int h = bid & 31, bc = bid >> 5;
    __shared__ _Float16 Bs2[2][64 * 128];
    __shared__ _Float16 PwF[4 * 64 * 64];
    __shared__ float cumL[256], dtL[256];
    const int t = threadIdx.x, w = t >> 6, ln = t & 63;
    const int lr = ln & 15, lg = ln >> 4;

    {
        cumL[t] = cumT[(size_t)bid * 256 + t];
        dtL[t]  = dtT[(size_t)bid * 256 + t];
    }
    {
        const float* sp = Sprev + (size_t)bid * (DHEAD * DSTATE);
        int r = t >> 2, cb = (t & 3) * 32;
        #pragma unroll
        for (int q = 0; q < 4; ++q) {
            int c = cb + q * 8;
            float4 f0 = *(const float4*)(sp + r * 128 + c);
            float4 f1 = *(const float4*)(sp + r * 128 + c + 4);
            half8 hv;
            hv[0]=(_Float16)f0.x; hv[1]=(_Float16)f0.y; hv[2]=(_Float16)f0.z; hv[3]=(_Float16)f0.w;
            hv[4]=(_Float16)f1.x; hv[5]=(_Float16)f1.y; hv[6]=(_Float16)f1.z; hv[7]=(_Float16)f1.w;
            *(half8*)(PwF + r * 128 + (c ^ ((r & 7) << 3))) = hv;
        }
    }
    {
        #pragma unroll
        for (int q = 0; q < 4; ++q) {
            int seg = w * 4 + q;
            int r = seg * 4 + lg;
            int csw = 8 * (lr ^ (r & 7));
            const _Float16* src = xbc + ((size_t)(bc * 256 + r)) * CONVDIM + DSSM + csw;
            gload_lds16(src, (void*)(Bs2[0] + seg * 512));
        }
    }
    half8 ca[4][4];
    {
        const _Float16* cb = xbc + ((size_t)(bc * 256 + w * 64)) * CONVDIM + CBASE;
        #pragma unroll
        for (int mi = 0; mi < 4; ++mi)
            #pragma unroll
            for (int kk = 0; kk < 4; ++kk)
                ca[mi][kk] = *(const half8*)(cb + (size_t)(mi * 16 + lr) * CONVDIM + kk * 32 + lg * 8);
    }
    __syncthreads();

    f32x4 yacc[4][4];
    #pragma unroll
    for (int i = 0; i < 4; ++i)
        #pragma unroll
        for (int j = 0; j < 4; ++j) { f32x4 z = {0.f,0.f,0.f,0.f}; yacc[i][j] = z; }

    #pragma unroll
    for (int kk = 0; kk < 4; ++kk) {
        int co = kk * 32 + lg * 8;
        #pragma unroll
        for (int pi = 0; pi < 4; ++pi) {
            int r = pi * 16 + lr;
            half8 pb = *(const half8*)(PwF + r * 128 + (co ^ ((r & 7) << 3)));
            #pragma unroll
            for (int mi = 0; mi < 4; ++mi)
                yacc[mi][pi] = __builtin_amdgcn_mfma_f32_16x16x32_f16(ca[mi][kk], pb, yacc[mi][pi], 0, 0, 0);
        }
    }
    #pragma unroll
    for (int mi = 0; mi < 4; ++mi)
        #pragma unroll
        for (int r = 0; r < 4; ++r) {
            float e = expf(cumL[w * 64 + mi * 16 + lg * 4 + r]);
            #pragma unroll
            for (int pi = 0; pi < 4; ++pi) yacc[mi][pi][r] *= e;
        }
    float c0 = cumL[w * 64];
    float el[4];
    #pragma unroll
    for (int mi = 0; mi < 4; ++mi) el[mi] = expf(cumL[w * 64 + mi * 16 + lr] - c0);
    float Dv = Dp[h];

    __syncthreads();

    _Float16* pwb = PwF + w * 4096;
    for (int st = 0; st < 4; ++st) {
        if (st < 3) {
            #pragma unroll
            for (int q = 0; q < 4; ++q) {
                int seg = w * 4 + q;
                int r = seg * 4 + lg;
                int csw = 8 * (lr ^ (r & 7));
                const _Float16* src = xbc + ((size_t)(bc * 256 + (st + 1) * 64 + r)) * CONVDIM + DSSM + csw;
                gload_lds16(src, (void*)(Bs2[(st + 1) & 1] + seg * 512));
            }
        }
        if (st <= w) {
            const _Float16* bsc = Bs2[st & 1];
            half8 xb[4][2];
            #pragma unroll
            for (int pi = 0; pi < 4; ++pi)
                #pragma unroll
                for (int k2 = 0; k2 < 2; ++k2)
                    xb[pi][k2] = *(const half8*)(xTg + ((size_t)bid * 64 + pi * 16 + lr) * 256
                                                 + st * 64 + k2 * 32 + lg * 8);
            #pragma unroll
            for (int si = 0; si < 4; ++si) {
                f32x4 ps[4];
                #pragma unroll
                for (int mi = 0; mi < 4; ++mi) { f32x4 z = {0.f,0.f,0.f,0.f}; ps[mi] = z; }
                int r = si * 16 + lr;
                #pragma unroll
                for (int kk = 0; kk < 4; ++kk) {
                    int co = kk * 32 + lg * 8;
                    half8 bb = *(const half8*)(bsc + r * 128 + (co ^ ((r & 7) << 3)));
                    #pragma unroll
                    for (int mi = 0; mi < 4; ++mi)
                        ps[mi] = __builtin_amdgcn_mfma_f32_16x16x32_f16(bb, ca[mi][kk], ps[mi], 0, 0, 0);
                }
                if (st < w) {
                    float fs[4];
                    #pragma unroll
                    for (int rr = 0; rr < 4; ++rr) {
                        int sg = st * 64 + si * 16 + lg * 4 + rr;
                        fs[rr] = expf(c0 - cumL[sg]) * dtL[sg];
                    }
                    #pragma unroll
                    for (int mi = 0; mi < 4; ++mi) {
                        half4 hv;
                        #pragma unroll
                        for (int rr = 0; rr < 4; ++rr)
                            hv[rr] = (_Float16)(ps[mi][rr] * el[mi] * fs[rr]);
                        *(half4*)(pwb + (mi * 16 + lr) * 64 + ((si * 16 + lg * 4) ^ (8 * (lr & 7)))) = hv;
                    }
                } else {
                    #pragma unroll
                    for (int mi = 0; mi < 4; ++mi) {
                        int lloc = mi * 16 + lr;
                        float cl = cumL[w * 64 + lloc];
                        half4 hv;
                        #pragma unroll
                        for (int rr = 0; rr < 4; ++rr) {
                            int sl = si * 16 + lg * 4 + rr;
                            float v = 0.f;
                            if (sl <= lloc) {
                                int sg = w * 64 + sl;
                                v = ps[mi][rr] * expf(cl - cumL[sg]) * dtL[sg];
                                if (sl == lloc) v += Dv;
                            }
                            hv[rr] = (_Float16)v;
                        }
                        *(half4*)(pwb + (mi * 16 + lr) * 64 + ((si * 16 + lg * 4) ^ (8 * (lr & 7)))) = hv;
                    }
                }
            }
            #pragma unroll
            for (int k2 = 0; k2 < 2; ++k2) {
                int co = k2 * 32 + lg * 8;
                half8 pa[4];
                #pragma unroll
                for (int mi = 0; mi < 4; ++mi) {
                    int r = mi * 16 + lr;
                    pa[mi] = *(const half8*)(pwb + r * 64 + (co ^ (8 * (lr & 7))));
                }
                #pragma unroll
                for (int pi = 0; pi < 4; ++pi)
                    #pragma unroll
                    for (int mi = 0; mi < 4; ++mi)
                        yacc[mi][pi] = __builtin_amdgcn_mfma_f32_16x16x32_f16(pa[mi], xb[pi][k2], yacc[mi][pi], 0, 0, 0);
            }
        }
        __syncthreads();
    }

    #pragma unroll
    for (int mi = 0; mi < 4; ++mi) {
        #pragma unroll
        for (int r = 0; r < 4; ++r) {
            int l = w * 64 + mi * 16 + lg * 4 + r;
            size_t row = (size_t)bc * 256 + l;
            #pragma unroll
            for (int pi = 0; pi < 4; ++pi)
                y[row * DSSM + h * 64 + pi * 16 + lr] = (_Float16)yacc[mi][pi][r];
        }
    }
}

// ---------------------------------------------------------------------------
// Gated RMSNorm (f16 y and z inputs) -> f16 output for out_proj MFMA
// ---------------------------------------------------------------------------
__global__ __launch_bounds__(256) void norm_kernel(const _Float16* __restrict__ y,
                                                   const _Float16* __restrict__ zx,
                                                   const float* __restrict__ norm_w,
                                                   _Float16* __restrict__ outh) {
    int m = blockIdx.x;
    int t = threadIdx.x;
    const _Float16* yrow = y + (size_t)m * DSSM;
    const _Float16* zrow = zx + (size_t)m * DINPROJ;
    float yg[8];
    float ss = 0.f;
    half8 zv = *(const half8*)(zrow + t * 8);
    half8 yv = *(const half8*)(yrow + t * 8);
    #pragma unroll
    for (int i = 0; i < 8; ++i) {
        float z = (float)zv[i];
        float sz = z / (1.f + expf(-z));
        float g = (float)yv[i] * sz;
        yg[i] = g;
        ss += g * g;
    }
    #pragma unroll
    for (int off = 32; off > 0; off >>= 1) ss += __shfl_xor(ss, off, 64);
    __shared__ float red[4];
    if ((t & 63) == 0) red[t >> 6] = ss;
    __syncthreads();
    float tot = red[0] + red[1] + red[2] + red[3];
    float inv = rsqrtf(tot / (float)DSSM + EPSF);
    half8 h;
    #pragma unroll
    for (int q = 0; q < 8; ++q)
        h[q] = (_Float16)(yg[q] * inv * norm_w[t*8 + q]);
    *(half8*)(outh + (size_t)m * DSSM + t * 8) = h;
}

// ---------------------------------------------------------------------------
extern "C" void kernel_launch(void* const* d_in, const int* in_sizes, int n_in,
                              void* d_out, int out_size, void* d_ws, size_t ws_size,
                              hipStream_t stream) {
    (void)in_sizes; (void)n_in; (void)out_size; (void)ws_size;
    const float* u       = (const float*)d_in[0];
    const float* W_in    = (const float*)d_in[1];
    const float* conv_w  = (const float*)d_in[2];
    const float* conv_b  = (const float*)d_in[3];
    const float* dt_bias = (const float*)d_in[4];
    const float* A_log   = (const float*)d_in[5];
    const float* Dp      = (const float*)d_in[6];
    const float* norm_w  = (const float*)d_in[7];
    const float* W_out   = (const float*)d_in[8];
    float* out = (float*)d_out;

    // workspace layout: f32 region first, then f16 region
    float* dtraw = (float*)d_ws;                       // NHEADS*ROWS (h-major)
    float* dtb   = dtraw + (size_t)ROWS * NHEADS;      // [(bc*32+h)*256+l]
    float* cum   = dtb   + (size_t)ROWS * NHEADS;
    float* Sbuf  = cum   + (size_t)ROWS * NHEADS;      // 512*64*128
    _Float16* zxh   = (_Float16*)(Sbuf + (size_t)NBC * NHEADS * DHEAD * DSTATE);
    _Float16* xbc_h = zxh   + (size_t)ROWS * DINPROJ;              // ROWS*CONVDIM
    _Float16* xTg   = xbc_h + (size_t)ROWS * CONVDIM;              // 512*64*256
    _Float16* BTg   = xTg   + (size_t)NBC * NHEADS * 64 * 256;     // 16*128*256
    _Float16* ybh16 = BTg   + (size_t)NBC * 128 * 256;             // ROWS*DSSM (y, f16)
    _Float16* uh    = ybh16 + (size_t)ROWS * DSSM;
    _Float16* Wih   = uh    + (size_t)ROWS * DMODEL;
    _Float16* Wouth = Wih   + (size_t)NPAD * DMODEL;
    _Float16* ygh   = Wouth + (size_t)DMODEL * DSSM;               // normed y, f16

    // casts
    cast_f16_kernel<<<(ROWS * DMODEL / 8 + 255) / 256, 256, 0, stream>>>(u, uh, ROWS * DMODEL / 8);
    cast_pad_f16_kernel<<<(NPAD * DMODEL / 8 + 255) / 256, 256, 0, stream>>>(
        W_in, Wih, DINPROJ, DMODEL, NPAD * DMODEL / 8);
    cast_f16_kernel<<<(DMODEL * DSSM / 8 + 255) / 256, 256, 0, stream>>>(W_out, Wouth, DMODEL * DSSM / 8);

    // 1. in_proj -> f16 zx (+ f32 h-major dt_raw side-channel)
    gemm_f16<4, 4, true><<<dim3(NPAD / 128, ROWS / 128), 256, 0, stream>>>(
        uh, Wih, (void*)zxh, dtraw, DMODEL, DINPROJ, DINPROJ);
    // 2. conv + silu -> f16 xbc + transposed copies
    conv_silu_kernel<<<NBC * 36, 256, 0, stream>>>(
        zxh, conv_w, conv_b, xbc_h, xTg, BTg);
    // 3. dt + cumsum (parallel block scan)
    dtcum_kernel<<<NBC * NHEADS, 256, 0, stream>>>(dtraw, dt_bias, A_log, dtb, cum);
    // 4. chunk states (MFMA)
    chunk_state_mfma<<<NBC * NHEADS, 256, 0, stream>>>(xTg, BTg, dtb, cum, Sbuf);
    // 5. inter-chunk scan (512 blocks)
    scan_kernel<<<NBC * NHEADS, 256, 0, stream>>>(cum, Sbuf);
    // 6. Y (MFMA v2, f16 out)
    y_mfma<<<NBC * NHEADS, 256, 0, stream>>>(xbc_h, xTg, dtb, cum, Sbuf, Dp, ybh16);
    // 7. gated RMSNorm -> f16
    norm_kernel<<<ROWS, 256, 0, stream>>>(ybh16, zxh, norm_w, ygh);
    // 8. out_proj (f32 out)
    gemm_f16<4, 2, false><<<dim3(DMODEL / 64, ROWS / 128), 256, 0, stream>>>(
        ygh, Wouth, (void*)out, nullptr, DSSM, DMODEL, DMODEL);
}

// Round 9
// 281.307 us; speedup vs baseline: 1.5597x; 1.0285x over previous
//
#include <hip/hip_runtime.h>
#include <hip/hip_bf16.h>
#include <math.h>
#include <stdint.h>

// Problem constants
#define BATCH    2
#define SEQ      2048
#define DMODEL   1024
#define DSSM     2048
#define NHEADS   32
#define DHEAD    64
#define DSTATE   128
#define CONVDIM  2304     // DSSM + 2*DSTATE
#define DINPROJ  4384     // 2*2048 + 2*128 + 32
#define NPAD     4608     // DINPROJ padded to 36*128 for 2D XCD regions
#define CHUNK    256
#define NCHUNK   8
#define ROWS     (BATCH*SEQ)          // 4096
#define NBC      (BATCH*NCHUNK)       // 16
#define EPSF     1e-5f
#define CBASE    (DSSM + DSTATE)      // 2176, C columns in xbc
#define DTCOL    (DSSM + CONVDIM)     // 4352, dt_raw columns start

typedef _Float16 half8 __attribute__((ext_vector_type(8)));
typedef _Float16 half4 __attribute__((ext_vector_type(4)));
typedef float f32x4 __attribute__((ext_vector_type(4)));

// global_load_lds: 16B per lane, LDS dest = wave-uniform base + lane*16
static __device__ __forceinline__ void gload_lds16(const void* g, void* l) {
    __builtin_amdgcn_global_load_lds(
        (const __attribute__((address_space(1))) uint32_t*)g,
        (__attribute__((address_space(3))) uint32_t*)l, 16, 0, 0);
}

// ---------------------------------------------------------------------------
// MFMA GEMM (f16 in): C[M,N] = A[M,K] * B[N,K]^T.  BK=64, XOR-swizzled LDS,
// 2-phase pipelined (dbuf LDS, prefetch before compute, setprio).
// SW2D: 2D XCD-region block swizzle (assumes grid 36x32, 8 regions of 16x9,
// XCD = bid%8). !SW2D: 1D contiguous-chunk XCD swizzle (nwg%8==0).
// HOUT: f16 C + f32 h-major dt_raw side-channel. !HOUT: f32 C.
// ---------------------------------------------------------------------------
template<int WM, int WN, bool HOUT, bool SW2D>
__global__ __launch_bounds__(256) void gemm_f16(const _Float16* __restrict__ A,
                                                const _Float16* __restrict__ B,
                                                void* __restrict__ Cout,
                                                float* __restrict__ dtraw,
                                                int K, int ldc, int Nc) {
    constexpr int BM = 32 * WM;
    constexpr int BN = 32 * WN;
    __shared__ _Float16 As[2][BM * 64];
    __shared__ _Float16 Bs[2][BN * 64];
    const int t  = threadIdx.x;
    const int wv = t >> 6;
    const int ln = t & 63;
    const int wr = wv >> 1, wc = wv & 1;

    int bid0 = blockIdx.y * gridDim.x + blockIdx.x;
    int tm, bn;
    if (SW2D) {
        // 8 XCD regions of 16 block-rows x 9 block-cols; XCD = bid0 % 8
        int r = bid0 & 7;
        int local = bid0 >> 3;            // 0..143
        int lr = local / 9;
        int lc = local - lr * 9;
        tm = (((r >> 2) * 16) + lr) * BM;
        bn = (((r & 3) * 9) + lc) * BN;
    } else {
        int nwg = gridDim.x * gridDim.y;
        int qq = nwg >> 3;
        int swz = (bid0 & 7) * qq + (bid0 >> 3);
        tm = (swz / gridDim.x) * BM;
        bn = (swz % gridDim.x) * BN;
    }

    const int kb = ln >> 4;          // 0..3
    const int lr = ln & 15;
    const int srow = ln >> 3;
    const int susw = (ln & 7) ^ srow;

    f32x4 acc[WM][WN];
    #pragma unroll
    for (int i = 0; i < WM; ++i)
        #pragma unroll
        for (int j = 0; j < WN; ++j) { f32x4 z = {0.f, 0.f, 0.f, 0.f}; acc[i][j] = z; }

    auto stage = [&](int buf, int k0) {
        #pragma unroll
        for (int q = 0; q < BM / 32; ++q) {
            int seg = q * 4 + wv;
            int row = seg * 8 + srow;
            const _Float16* src = A + (size_t)(tm + row) * K + k0 + susw * 8;
            gload_lds16(src, (void*)(As[buf] + seg * 512));
        }
        #pragma unroll
        for (int q = 0; q < BN / 32; ++q) {
            int seg = q * 4 + wv;
            int row = seg * 8 + srow;
            const _Float16* src = B + (size_t)(bn + row) * K + k0 + susw * 8;
            gload_lds16(src, (void*)(Bs[buf] + seg * 512));
        }
    };

    stage(0, 0);
    __syncthreads();
    int cur = 0;

    for (int k0 = 0; k0 < K; k0 += 64) {
        if (k0 + 64 < K) stage(cur ^ 1, k0 + 64);   // prefetch next tile

        __builtin_amdgcn_s_setprio(1);
        #pragma unroll
        for (int ks = 0; ks < 2; ++ks) {
            half8 af[WM], bf[WN];
            #pragma unroll
            for (int mi = 0; mi < WM; ++mi) {
                int r = wr * (16 * WM) + mi * 16 + lr;
                af[mi] = *(const half8*)(As[cur] + r * 64 + (((ks * 4 + kb) ^ (r & 7)) << 3));
            }
            #pragma unroll
            for (int ni = 0; ni < WN; ++ni) {
                int r = wc * (16 * WN) + ni * 16 + lr;
                bf[ni] = *(const half8*)(Bs[cur] + r * 64 + (((ks * 4 + kb) ^ (r & 7)) << 3));
            }
            #pragma unroll
            for (int mi = 0; mi < WM; ++mi)
                #pragma unroll
                for (int ni = 0; ni < WN; ++ni)
                    acc[mi][ni] = __builtin_amdgcn_mfma_f32_16x16x32_f16(af[mi], bf[ni], acc[mi][ni], 0, 0, 0);
        }
        __builtin_amdgcn_s_setprio(0);
        __syncthreads();
        cur ^= 1;
    }

    #pragma unroll
    for (int mi = 0; mi < WM; ++mi) {
        #pragma unroll
        for (int ni = 0; ni < WN; ++ni) {
            int col = bn + wc * (16 * WN) + ni * 16 + lr;
            if (col < Nc) {
                int row = tm + wr * (16 * WM) + mi * 16 + (ln >> 4) * 4;
                if (HOUT) {
                    _Float16* C = (_Float16*)Cout;
                    #pragma unroll
                    for (int r = 0; r < 4; ++r)
                        C[(size_t)(row + r) * ldc + col] = (_Float16)acc[mi][ni][r];
                    if (col >= DTCOL) {
                        #pragma unroll
                        for (int r = 0; r < 4; ++r)
                            dtraw[(size_t)(col - DTCOL) * ROWS + row + r] = acc[mi][ni][r];
                    }
                } else {
                    float* C = (float*)Cout;
                    #pragma unroll
                    for (int r = 0; r < 4; ++r)
                        C[(size_t)(row + r) * ldc + col] = acc[mi][ni][r];
                }
            }
        }
    }
}

// ---------------------------------------------------------------------------
// Fused casts: u -> uh, W_in (pad rows to NPAD) -> Wih, W_out -> Wouth
// ---------------------------------------------------------------------------
#define CAST_N1 (ROWS * DMODEL / 8)
#define CAST_N2 (CAST_N1 + NPAD * DMODEL / 8)
#define CAST_N3 (CAST_N2 + DMODEL * DSSM / 8)

__global__ __launch_bounds__(256) void cast_all_kernel(const float* __restrict__ u,
                                                       const float* __restrict__ Win,
                                                       const float* __restrict__ Wout,
                                                       _Float16* __restrict__ uh,
                                                       _Float16* __restrict__ Wih,
                                                       _Float16* __restrict__ Wouth) {
    int i = blockIdx.x * 256 + threadIdx.x;
    if (i >= CAST_N3) return;
    const float* src;
    _Float16* dst;
    int j;
    bool zero = false;
    if (i < CAST_N1) {
        src = u; dst = uh; j = i;
    } else if (i < CAST_N2) {
        j = i - CAST_N1;
        int row = (j * 8) / DMODEL;
        src = Win; dst = Wih;
        zero = (row >= DINPROJ);
    } else {
        j = i - CAST_N2;
        src = Wout; dst = Wouth;
    }
    half8 h;
    if (!zero) {
        float4 a = ((const float4*)src)[2 * j];
        float4 b = ((const float4*)src)[2 * j + 1];
        h[0] = (_Float16)a.x; h[1] = (_Float16)a.y; h[2] = (_Float16)a.z; h[3] = (_Float16)a.w;
        h[4] = (_Float16)b.x; h[5] = (_Float16)b.y; h[6] = (_Float16)b.z; h[7] = (_Float16)b.w;
    } else {
        #pragma unroll
        for (int q = 0; q < 8; ++q) h[q] = (_Float16)0.f;
    }
    ((half8*)dst)[j] = h;
}

// ---------------------------------------------------------------------------
// Conv + SiLU (f16 zx input), tiled with LDS transpose.
// ---------------------------------------------------------------------------
__global__ __launch_bounds__(256) void conv_silu_kernel(const _Float16* __restrict__ zx,
                                                        const float* __restrict__ conv_w,
                                                        const float* __restrict__ conv_b,
                                                        _Float16* __restrict__ xbc,
                                                        _Float16* __restrict__ xTg,
                                                        _Float16* __restrict__ BTg) {
    __shared__ float zs[67 * 64];
    __shared__ float os[64 * 65];
    const int bid = blockIdx.x;
    const int cg = bid % 36;
    const int bc = bid / 36;
    const int b = bc >> 3, cloc = bc & 7;
    const int c0 = cg * 64;
    const int t = threadIdx.x;

    const int cc = c0 + (t & 63);
    const float w0 = conv_w[cc * 4 + 0], w1 = conv_w[cc * 4 + 1];
    const float w2 = conv_w[cc * 4 + 2], w3 = conv_w[cc * 4 + 3];
    const float bias = conv_b[cc];

    for (int lt = 0; lt < 4; ++lt) {
        const int lbase = cloc * 256 + lt * 64;
        __syncthreads();
        for (int i = t; i < 67 * 64; i += 256) {
            int r = i >> 6, col = i & 63;
            int lseq = lbase - 3 + r;
            float v = 0.f;
            if (lseq >= 0)
                v = (float)zx[((size_t)(b * SEQ + lseq)) * DINPROJ + DSSM + c0 + col];
            zs[i] = v;
        }
        __syncthreads();
        {
            int c = t & 63;
            int w = t >> 6;
            #pragma unroll
            for (int j = 0; j < 16; ++j) {
                int l = w * 16 + j;
                float acc = bias + zs[(l + 0) * 64 + c] * w0 + zs[(l + 1) * 64 + c] * w1
                                 + zs[(l + 2) * 64 + c] * w2 + zs[(l + 3) * 64 + c] * w3;
                os[l * 65 + c] = acc / (1.f + expf(-acc));
            }
        }
        __syncthreads();
        {
            int l = t >> 2, cs = (t & 3) * 16;
            size_t m = (size_t)(b * SEQ + lbase + l);
            half8 h0, h1;
            #pragma unroll
            for (int i = 0; i < 8; ++i) h0[i] = (_Float16)os[l * 65 + cs + i];
            #pragma unroll
            for (int i = 0; i < 8; ++i) h1[i] = (_Float16)os[l * 65 + cs + 8 + i];
            _Float16* dst = xbc + m * CONVDIM + c0 + cs;
            *(half8*)dst = h0;
            *(half8*)(dst + 8) = h1;
        }
        if (c0 < CBASE) {
            int c = t >> 2, ls = (t & 3) * 16;
            int gc = c0 + c;
            half8 h0, h1;
            #pragma unroll
            for (int i = 0; i < 8; ++i) h0[i] = (_Float16)os[(ls + i) * 65 + c];
            #pragma unroll
            for (int i = 0; i < 8; ++i) h1[i] = (_Float16)os[(ls + 8 + i) * 65 + c];
            _Float16* dst;
            if (gc < DSSM)
                dst = xTg + ((size_t)bc * 2048 + gc) * 256 + lt * 64 + ls;
            else
                dst = BTg + ((size_t)bc * 128 + (gc - DSSM)) * 256 + lt * 64 + ls;
            *(half8*)dst = h0;
            *(half8*)(dst + 8) = h1;
        }
    }
}

// ---------------------------------------------------------------------------
// Parallel dt+cumsum: one block per (bc,h).
// ---------------------------------------------------------------------------
__global__ __launch_bounds__(256) void dtcum_kernel(const float* __restrict__ dtraw,
                                                    const float* __restrict__ dt_bias,
                                                    const float* __restrict__ A_log,
                                                    float* __restrict__ dtT,
                                                    float* __restrict__ cumT) {
    __shared__ float sv[256];
    const int bid = blockIdx.x;          // bc*32 + h
    const int h = bid & 31, bc = bid >> 5;
    const int t = threadIdx.x;
    float v = dtraw[(size_t)h * ROWS + bc * 256 + t] + dt_bias[h];
    float d = (v > 20.f) ? v : log1pf(expf(v));
    float A = -expf(A_log[h]);
    dtT[(size_t)bid * 256 + t] = d;
    sv[t] = d * A;
    #pragma unroll
    for (int off = 1; off < 256; off <<= 1) {
        __syncthreads();
        float add = (t >= off) ? sv[t - off] : 0.f;
        __syncthreads();
        sv[t] += add;
    }
    __syncthreads();
    cumT[(size_t)bid * 256 + t] = sv[t];
}

// ---------------------------------------------------------------------------
// Chunk states via MFMA: S[p][n] = sum_l (coef[l]*x[l,p]) * B[l,n]
// ---------------------------------------------------------------------------
__global__ __launch_bounds__(256) void chunk_state_mfma(const _Float16* __restrict__ xTg,
                                                        const _Float16* __restrict__ BTg,
                                                        const float* __restrict__ dtT,
                                                        const float* __restrict__ cumT,
                                                        float* __restrict__ S) {
    int bid = blockIdx.x;
    int bc = bid >> 5;
    __shared__ _Float16 cxs[64 * 64];
    __shared__ _Float16 bts[128 * 64];
    __shared__ float coefL[256];
    const int t = threadIdx.x, w = t >> 6, ln = t & 63;
    const int lr = ln & 15, lg = ln >> 4;

    {
        float cl = cumT[(size_t)bid * 256 + 255];
        coefL[t] = expf(cl - cumT[(size_t)bid * 256 + t]) * dtT[(size_t)bid * 256 + t];
    }

    f32x4 sacc[4][2];
    #pragma unroll
    for (int pi = 0; pi < 4; ++pi)
        #pragma unroll
        for (int ni = 0; ni < 2; ++ni) { f32x4 z = {0.f,0.f,0.f,0.f}; sacc[pi][ni] = z; }

    const _Float16* xTh = xTg + (size_t)bid * 64 * 256;

    for (int kt = 0; kt < 4; ++kt) {
        __syncthreads();
        {
            int p = t >> 2, l0 = (t & 3) * 16;
            const _Float16* src = xTh + (size_t)p * 256 + kt * 64;
            #pragma unroll
            for (int q = 0; q < 2; ++q) {
                int c = l0 + q * 8;
                half8 hv = *(const half8*)(src + c);
                half8 ov;
                #pragma unroll
                for (int j = 0; j < 8; ++j)
                    ov[j] = (_Float16)((float)hv[j] * coefL[kt * 64 + c + j]);
                *(half8*)(cxs + p * 64 + (c ^ ((p & 7) << 3))) = ov;
            }
        }
        #pragma unroll
        for (int q = 0; q < 4; ++q) {
            int seg = w * 4 + q;
            int r = seg * 8 + (ln >> 3);
            int csw = 8 * ((ln & 7) ^ (r & 7));
            const _Float16* src = BTg + ((size_t)bc * 128 + r) * 256 + kt * 64 + csw;
            gload_lds16(src, (void*)(bts + seg * 512));
        }
        __syncthreads();
        #pragma unroll
        for (int kk = 0; kk < 2; ++kk) {
            int c0 = kk * 32 + lg * 8;
            half8 ax[4], bx[2];
            #pragma unroll
            for (int pi = 0; pi < 4; ++pi) {
                int r = pi * 16 + lr;
                ax[pi] = *(const half8*)(cxs + r * 64 + (c0 ^ ((r & 7) << 3)));
            }
            #pragma unroll
            for (int ni = 0; ni < 2; ++ni) {
                int r = w * 32 + ni * 16 + lr;
                bx[ni] = *(const half8*)(bts + r * 64 + (c0 ^ ((r & 7) << 3)));
            }
            #pragma unroll
            for (int pi = 0; pi < 4; ++pi)
                #pragma unroll
                for (int ni = 0; ni < 2; ++ni)
                    sacc[pi][ni] = __builtin_amdgcn_mfma_f32_16x16x32_f16(ax[pi], bx[ni], sacc[pi][ni], 0, 0, 0);
        }
    }
    float* sb = S + (size_t)bid * (DHEAD * DSTATE);
    #pragma unroll
    for (int pi = 0; pi < 4; ++pi)
        #pragma unroll
        for (int ni = 0; ni < 2; ++ni)
            #pragma unroll
            for (int r = 0; r < 4; ++r) {
                int p = pi * 16 + lg * 4 + r;
                int n = w * 32 + ni * 16 + lr;
                sb[p * 128 + n] = sacc[pi][ni][r];
            }
}

// ---------------------------------------------------------------------------
// Inter-chunk scan; S[c] <- state ENTERING chunk c.  512 blocks.
// ---------------------------------------------------------------------------
__global__ __launch_bounds__(256) void scan_kernel(const float* __restrict__ cumT,
                                                   float* __restrict__ S) {
    int bid = blockIdx.x;
    int part = bid & 7;
    int bh = bid >> 3;               // b*32 + h
    int h = bh & 31, b = bh >> 5;
    int t = threadIdx.x;
    float carry[4];
    #pragma unroll
    for (int i = 0; i < 4; ++i) carry[i] = 0.f;
    for (int c = 0; c < NCHUNK; ++c) {
        int bc = b * NCHUNK + c;
        float decay = expf(cumT[((size_t)(bc * 32 + h)) * 256 + 255]);
        size_t base = ((size_t)(bc * 32 + h)) * (DHEAD * DSTATE) + part * 1024;
        #pragma unroll
        for (int i = 0; i < 4; ++i) {
            size_t idx = base + t + i * 256;
            float s = S[idx];
            float nw = carry[i] * decay + s;
            S[idx] = carry[i];
            carry[i] = nw;
        }
    }
}

// ---------------------------------------------------------------------------
// Y via MFMA v2 (f16 output)
// ---------------------------------------------------------------------------
__global__ __launch_bounds__(256, 2) void y_mfma(const _Float16* __restrict__ xbc,
                                                 const _Float16* __restrict__ xTg,
                                                 const float* __restrict__ dtT,
                                                 const float* __restrict__ cumT,
                                                 const float* __restrict__ Sprev,
                                                 const float* __restrict__ Dp,
                                                 _Float16* __restrict__ y) {
    int bid = blockIdx.x;
    int h = bid & 31, bc = bid >> 5;
    __shared__ _Float16 Bs2[2][64 * 128];
    __shared__ _Float16 PwF[4 * 64 * 64];
    __shared__ float cumL[256], dtL[256];
    const int t = threadIdx.x, w = t >> 6, ln = t & 63;
    const int lr = ln & 15, lg = ln >> 4;

    {
        cumL[t] = cumT[(size_t)bid * 256 + t];
        dtL[t]  = dtT[(size_t)bid * 256 + t];
    }
    {
        const float* sp = Sprev + (size_t)bid * (DHEAD * DSTATE);
        int r = t >> 2, cb = (t & 3) * 32;
        #pragma unroll
        for (int q = 0; q < 4; ++q) {
            int c = cb + q * 8;
            float4 f0 = *(const float4*)(sp + r * 128 + c);
            float4 f1 = *(const float4*)(sp + r * 128 + c + 4);
            half8 hv;
            hv[0]=(_Float16)f0.x; hv[1]=(_Float16)f0.y; hv[2]=(_Float16)f0.z; hv[3]=(_Float16)f0.w;
            hv[4]=(_Float16)f1.x; hv[5]=(_Float16)f1.y; hv[6]=(_Float16)f1.z; hv[7]=(_Float16)f1.w;
            *(half8*)(PwF + r * 128 + (c ^ ((r & 7) << 3))) = hv;
        }
    }
    {
        #pragma unroll
        for (int q = 0; q < 4; ++q) {
            int seg = w * 4 + q;
            int r = seg * 4 + lg;
            int csw = 8 * (lr ^ (r & 7));
            const _Float16* src = xbc + ((size_t)(bc * 256 + r)) * CONVDIM + DSSM + csw;
            gload_lds16(src, (void*)(Bs2[0] + seg * 512));
        }
    }
    half8 ca[4][4];
    {
        const _Float16* cb = xbc + ((size_t)(bc * 256 + w * 64)) * CONVDIM + CBASE;
        #pragma unroll
        for (int mi = 0; mi < 4; ++mi)
            #pragma unroll
            for (int kk = 0; kk < 4; ++kk)
                ca[mi][kk] = *(const half8*)(cb + (size_t)(mi * 16 + lr) * CONVDIM + kk * 32 + lg * 8);
    }
    __syncthreads();

    f32x4 yacc[4][4];
    #pragma unroll
    for (int i = 0; i < 4; ++i)
        #pragma unroll
        for (int j = 0; j < 4; ++j) { f32x4 z = {0.f,0.f,0.f,0.f}; yacc[i][j] = z; }

    #pragma unroll
    for (int kk = 0; kk < 4; ++kk) {
        int co = kk * 32 + lg * 8;
        #pragma unroll
        for (int pi = 0; pi < 4; ++pi) {
            int r = pi * 16 + lr;
            half8 pb = *(const half8*)(PwF + r * 128 + (co ^ ((r & 7) << 3)));
            #pragma unroll
            for (int mi = 0; mi < 4; ++mi)
                yacc[mi][pi] = __builtin_amdgcn_mfma_f32_16x16x32_f16(ca[mi][kk], pb, yacc[mi][pi], 0, 0, 0);
        }
    }
    #pragma unroll
    for (int mi = 0; mi < 4; ++mi)
        #pragma unroll
        for (int r = 0; r < 4; ++r) {
            float e = expf(cumL[w * 64 + mi * 16 + lg * 4 + r]);
            #pragma unroll
            for (int pi = 0; pi < 4; ++pi) yacc[mi][pi][r] *= e;
        }
    float c0 = cumL[w * 64];
    float el[4];
    #pragma unroll
    for (int mi = 0; mi < 4; ++mi) el[mi] = expf(cumL[w * 64 + mi * 16 + lr] - c0);
    float Dv = Dp[h];

    __syncthreads();

    _Float16* pwb = PwF + w * 4096;
    for (int st = 0; st < 4; ++st) {
        if (st < 3) {
            #pragma unroll
            for (int q = 0; q < 4; ++q) {
                int seg = w * 4 + q;
                int r = seg * 4 + lg;
                int csw = 8 * (lr ^ (r & 7));
                const _Float16* src = xbc + ((size_t)(bc * 256 + (st + 1) * 64 + r)) * CONVDIM + DSSM + csw;
                gload_lds16(src, (void*)(Bs2[(st + 1) & 1] + seg * 512));
            }
        }
        if (st <= w) {
            const _Float16* bsc = Bs2[st & 1];
            half8 xb[4][2];
            #pragma unroll
            for (int pi = 0; pi < 4; ++pi)
                #pragma unroll
                for (int k2 = 0; k2 < 2; ++k2)
                    xb[pi][k2] = *(const half8*)(xTg + ((size_t)bid * 64 + pi * 16 + lr) * 256
                                                 + st * 64 + k2 * 32 + lg * 8);
            #pragma unroll
            for (int si = 0; si < 4; ++si) {
                f32x4 ps[4];
                #pragma unroll
                for (int mi = 0; mi < 4; ++mi) { f32x4 z = {0.f,0.f,0.f,0.f}; ps[mi] = z; }
                int r = si * 16 + lr;
                #pragma unroll
                for (int kk = 0; kk < 4; ++kk) {
                    int co = kk * 32 + lg * 8;
                    half8 bb = *(const half8*)(bsc + r * 128 + (co ^ ((r & 7) << 3)));
                    #pragma unroll
                    for (int mi = 0; mi < 4; ++mi)
                        ps[mi] = __builtin_amdgcn_mfma_f32_16x16x32_f16(bb, ca[mi][kk], ps[mi], 0, 0, 0);
                }
                if (st < w) {
                    float fs[4];
                    #pragma unroll
                    for (int rr = 0; rr < 4; ++rr) {
                        int sg = st * 64 + si * 16 + lg * 4 + rr;
                        fs[rr] = expf(c0 - cumL[sg]) * dtL[sg];
                    }
                    #pragma unroll
                    for (int mi = 0; mi < 4; ++mi) {
                        half4 hv;
                        #pragma unroll
                        for (int rr = 0; rr < 4; ++rr)
                            hv[rr] = (_Float16)(ps[mi][rr] * el[mi] * fs[rr]);
                        *(half4*)(pwb + (mi * 16 + lr) * 64 + ((si * 16 + lg * 4) ^ (8 * (lr & 7)))) = hv;
                    }
                } else {
                    #pragma unroll
                    for (int mi = 0; mi < 4; ++mi) {
                        int lloc = mi * 16 + lr;
                        float cl = cumL[w * 64 + lloc];
                        half4 hv;
                        #pragma unroll
                        for (int rr = 0; rr < 4; ++rr) {
                            int sl = si * 16 + lg * 4 + rr;
                            float v = 0.f;
                            if (sl <= lloc) {
                                int sg = w * 64 + sl;
                                v = ps[mi][rr] * expf(cl - cumL[sg]) * dtL[sg];
                                if (sl == lloc) v += Dv;
                            }
                            hv[rr] = (_Float16)v;
                        }
                        *(half4*)(pwb + (mi * 16 + lr) * 64 + ((si * 16 + lg * 4) ^ (8 * (lr & 7)))) = hv;
                    }
                }
            }
            #pragma unroll
            for (int k2 = 0; k2 < 2; ++k2) {
                int co = k2 * 32 + lg * 8;
                half8 pa[4];
                #pragma unroll
                for (int mi = 0; mi < 4; ++mi) {
                    int r = mi * 16 + lr;
                    pa[mi] = *(const half8*)(pwb + r * 64 + (co ^ (8 * (lr & 7))));
                }
                #pragma unroll
                for (int pi = 0; pi < 4; ++pi)
                    #pragma unroll
                    for (int mi = 0; mi < 4; ++mi)
                        yacc[mi][pi] = __builtin_amdgcn_mfma_f32_16x16x32_f16(pa[mi], xb[pi][k2], yacc[mi][pi], 0, 0, 0);
            }
        }
        __syncthreads();
    }

    #pragma unroll
    for (int mi = 0; mi < 4; ++mi) {
        #pragma unroll
        for (int r = 0; r < 4; ++r) {
            int l = w * 64 + mi * 16 + lg * 4 + r;
            size_t row = (size_t)bc * 256 + l;
            #pragma unroll
            for (int pi = 0; pi < 4; ++pi)
                y[row * DSSM + h * 64 + pi * 16 + lr] = (_Float16)yacc[mi][pi][r];
        }
    }
}

// ---------------------------------------------------------------------------
// Gated RMSNorm (f16 y and z inputs) -> f16 output for out_proj MFMA
// ---------------------------------------------------------------------------
__global__ __launch_bounds__(256) void norm_kernel(const _Float16* __restrict__ y,
                                                   const _Float16* __restrict__ zx,
                                                   const float* __restrict__ norm_w,
                                                   _Float16* __restrict__ outh) {
    int m = blockIdx.x;
    int t = threadIdx.x;
    const _Float16* yrow = y + (size_t)m * DSSM;
    const _Float16* zrow = zx + (size_t)m * DINPROJ;
    float yg[8];
    float ss = 0.f;
    half8 zv = *(const half8*)(zrow + t * 8);
    half8 yv = *(const half8*)(yrow + t * 8);
    #pragma unroll
    for (int i = 0; i < 8; ++i) {
        float z = (float)zv[i];
        float sz = z / (1.f + expf(-z));
        float g = (float)yv[i] * sz;
        yg[i] = g;
        ss += g * g;
    }
    #pragma unroll
    for (int off = 32; off > 0; off >>= 1) ss += __shfl_xor(ss, off, 64);
    __shared__ float red[4];
    if ((t & 63) == 0) red[t >> 6] = ss;
    __syncthreads();
    float tot = red[0] + red[1] + red[2] + red[3];
    float inv = rsqrtf(tot / (float)DSSM + EPSF);
    half8 h;
    #pragma unroll
    for (int q = 0; q < 8; ++q)
        h[q] = (_Float16)(yg[q] * inv * norm_w[t*8 + q]);
    *(half8*)(outh + (size_t)m * DSSM + t * 8) = h;
}

// ---------------------------------------------------------------------------
extern "C" void kernel_launch(void* const* d_in, const int* in_sizes, int n_in,
                              void* d_out, int out_size, void* d_ws, size_t ws_size,
                              hipStream_t stream) {
    (void)in_sizes; (void)n_in; (void)out_size; (void)ws_size;
    const float* u       = (const float*)d_in[0];
    const float* W_in    = (const float*)d_in[1];
    const float* conv_w  = (const float*)d_in[2];
    const float* conv_b  = (const float*)d_in[3];
    const float* dt_bias = (const float*)d_in[4];
    const float* A_log   = (const float*)d_in[5];
    const float* Dp      = (const float*)d_in[6];
    const float* norm_w  = (const float*)d_in[7];
    const float* W_out   = (const float*)d_in[8];
    float* out = (float*)d_out;

    // workspace layout: f32 region first, then f16 region
    float* dtraw = (float*)d_ws;                       // NHEADS*ROWS (h-major)
    float* dtb   = dtraw + (size_t)ROWS * NHEADS;      // [(bc*32+h)*256+l]
    float* cum   = dtb   + (size_t)ROWS * NHEADS;
    float* Sbuf  = cum   + (size_t)ROWS * NHEADS;      // 512*64*128
    _Float16* zxh   = (_Float16*)(Sbuf + (size_t)NBC * NHEADS * DHEAD * DSTATE);
    _Float16* xbc_h = zxh   + (size_t)ROWS * DINPROJ;              // ROWS*CONVDIM
    _Float16* xTg   = xbc_h + (size_t)ROWS * CONVDIM;              // 512*64*256
    _Float16* BTg   = xTg   + (size_t)NBC * NHEADS * 64 * 256;     // 16*128*256
    _Float16* ybh16 = BTg   + (size_t)NBC * 128 * 256;             // ROWS*DSSM (y, f16)
    _Float16* uh    = ybh16 + (size_t)ROWS * DSSM;
    _Float16* Wih   = uh    + (size_t)ROWS * DMODEL;               // NPAD x DMODEL
    _Float16* Wouth = Wih   + (size_t)NPAD * DMODEL;
    _Float16* ygh   = Wouth + (size_t)DMODEL * DSSM;               // normed y, f16

    // 0. fused casts
    cast_all_kernel<<<(CAST_N3 + 255) / 256, 256, 0, stream>>>(
        u, W_in, W_out, uh, Wih, Wouth);

    // 1. in_proj -> f16 zx (+ f32 h-major dt_raw side-channel); 2D XCD swizzle
    gemm_f16<4, 4, true, true><<<dim3(NPAD / 128, ROWS / 128), 256, 0, stream>>>(
        uh, Wih, (void*)zxh, dtraw, DMODEL, DINPROJ, DINPROJ);
    // 2. conv + silu -> f16 xbc + transposed copies
    conv_silu_kernel<<<NBC * 36, 256, 0, stream>>>(
        zxh, conv_w, conv_b, xbc_h, xTg, BTg);
    // 3. dt + cumsum (parallel block scan)
    dtcum_kernel<<<NBC * NHEADS, 256, 0, stream>>>(dtraw, dt_bias, A_log, dtb, cum);
    // 4. chunk states (MFMA)
    chunk_state_mfma<<<NBC * NHEADS, 256, 0, stream>>>(xTg, BTg, dtb, cum, Sbuf);
    // 5. inter-chunk scan (512 blocks)
    scan_kernel<<<NBC * NHEADS, 256, 0, stream>>>(cum, Sbuf);
    // 6. Y (MFMA v2, f16 out)
    y_mfma<<<NBC * NHEADS, 256, 0, stream>>>(xbc_h, xTg, dtb, cum, Sbuf, Dp, ybh16);
    // 7. gated RMSNorm -> f16
    norm_kernel<<<ROWS, 256, 0, stream>>>(ybh16, zxh, norm_w, ygh);
    // 8. out_proj (f32 out, 1D swizzle)
    gemm_f16<4, 2, false, false><<<dim3(DMODEL / 64, ROWS / 128), 256, 0, stream>>>(
        ygh, Wouth, (void*)out, nullptr, DSSM, DMODEL, DMODEL);
}